// Round 1
// baseline (1165.470 us; speedup 1.0000x reference)
//
#include <hip/hip_runtime.h>
#include <cstdint>
#include <cstddef>

#define N_NODES 50000
#define N_EDGES 800000
#define INC 128
#define HID 32
#define HEADS 8
#define OUTC 64
#define F1 (HEADS * HID) /* 256 */
#define NEG 0.2f

// ---------------------------------------------------------------------------
// Tiled fp32 GEMM: C[M,N] = A[M,K] @ B[K,N]   (N % BN == 0, K % BK == 0)
// BM=BN=64, BK=16, TM=TN=4, 256 threads. fp32 vector-ALU (no fp32 MFMA on CDNA4).
// ---------------------------------------------------------------------------
template <int BM, int BN, int BK, int TM, int TN>
__global__ __launch_bounds__((BM / TM) * (BN / TN)) void sgemm(
    const float* __restrict__ A, const float* __restrict__ B,
    float* __restrict__ C, int M, int N, int K) {
  constexpr int THREADS = (BM / TM) * (BN / TN);
  static_assert(BM * BK / 4 == THREADS, "A tile load mapping");
  static_assert(BK * BN / 4 == THREADS, "B tile load mapping");
  static_assert(TM == 4 && TN == 4, "float4 store path assumes 4x4");

  __shared__ float As[BK][BM + 4];  // +4 pad: 16B-aligned rows, conflict-light writes
  __shared__ float Bs[BK][BN];

  const int tid = threadIdx.x;
  const int brow = blockIdx.y, bcol = blockIdx.x;
  const int tr = tid / (BN / TN);
  const int tc = tid % (BN / TN);

  float acc[TM][TN] = {};

  for (int k0 = 0; k0 < K; k0 += BK) {
    {  // A tile: each thread one float4 along K (coalesced), scatter into As[k][m]
      int m = tid / (BK / 4);
      int kv = (tid % (BK / 4)) * 4;
      int gm = brow * BM + m;
      float4 v = make_float4(0.f, 0.f, 0.f, 0.f);
      if (gm < M) v = *reinterpret_cast<const float4*>(&A[(size_t)gm * K + k0 + kv]);
      As[kv + 0][m] = v.x;
      As[kv + 1][m] = v.y;
      As[kv + 2][m] = v.z;
      As[kv + 3][m] = v.w;
    }
    {  // B tile: each thread one float4 along N (coalesced), contiguous LDS write
      int k = tid / (BN / 4);
      int nv = (tid % (BN / 4)) * 4;
      *reinterpret_cast<float4*>(&Bs[k][nv]) =
          *reinterpret_cast<const float4*>(&B[(size_t)(k0 + k) * N + bcol * BN + nv]);
    }
    __syncthreads();
#pragma unroll
    for (int k = 0; k < BK; ++k) {
      float a[TM], b[TN];
#pragma unroll
      for (int i = 0; i < TM; i++) a[i] = As[k][tr * TM + i];
#pragma unroll
      for (int j = 0; j < TN; j++) b[j] = Bs[k][tc * TN + j];
#pragma unroll
      for (int i = 0; i < TM; i++)
#pragma unroll
        for (int j = 0; j < TN; j++) acc[i][j] += a[i] * b[j];
    }
    __syncthreads();
  }

#pragma unroll
  for (int i = 0; i < TM; i++) {
    int gm = brow * BM + tr * TM + i;
    if (gm >= M) break;  // rows are consecutive; safe to stop
    float4 v = make_float4(acc[i][0], acc[i][1], acc[i][2], acc[i][3]);
    *reinterpret_cast<float4*>(&C[(size_t)gm * N + bcol * BN + tc * TN]) = v;
  }
}

// ---------------------------------------------------------------------------
// alpha_s / alpha_d per (node, head): dot of h[n, h*C : h*C+C] with a vectors
// ---------------------------------------------------------------------------
template <int H, int C>
__global__ void alpha_kernel(const float* __restrict__ h,
                             const float* __restrict__ a_src,
                             const float* __restrict__ a_dst,
                             float* __restrict__ as, float* __restrict__ ad) {
  int tid = blockIdx.x * blockDim.x + threadIdx.x;
  if (tid >= N_NODES * H) return;
  int n = tid / H, hh = tid % H;
  const float* hp = h + (size_t)n * (H * C) + hh * C;
  const float* sv = a_src + hh * C;
  const float* dv = a_dst + hh * C;
  float s = 0.f, d = 0.f;
#pragma unroll
  for (int k = 0; k < C; k++) {
    float v = hp[k];
    s += v * sv[k];
    d += v * dv[k];
  }
  as[tid] = s;
  ad[tid] = d;
}

// ---------------------------------------------------------------------------
// Per-edge score: w = exp(leakyrelu(as[src] + ad[dst])); z[dst] += w.
// Max-shift dropped: scores are O(+-2) (weights scaled 0.05), exp is safe in
// fp32 and softmax is shift-invariant -> identical alpha.
// ---------------------------------------------------------------------------
template <int H>
__global__ void edge_score(const int* __restrict__ src, const int* __restrict__ dst,
                           const float* __restrict__ as, const float* __restrict__ ad,
                           float* __restrict__ w, float* __restrict__ z) {
  size_t tid = blockIdx.x * (size_t)blockDim.x + threadIdx.x;
  if (tid >= (size_t)N_EDGES * H) return;
  int e = (int)(tid / H), hh = (int)(tid % H);
  int s = src[e], d = dst[e];
  float v = as[(size_t)s * H + hh] + ad[(size_t)d * H + hh];
  v = (v >= 0.f) ? v : NEG * v;
  float ev = expf(v);
  w[tid] = ev;
  atomicAdd(&z[(size_t)d * H + hh], ev);
}

// ---------------------------------------------------------------------------
// Message scatter: out[dst, i] += h[src, i] * (w[e,h] / z[dst,h])
// One thread per (edge, feature). Coalesced 1KB gather + 1KB atomic per edge.
// ---------------------------------------------------------------------------
template <int H, int C>
__global__ void edge_aggr(const int* __restrict__ src, const int* __restrict__ dst,
                          const float* __restrict__ hfeat, const float* __restrict__ w,
                          const float* __restrict__ z, float* __restrict__ outp) {
  size_t tid = blockIdx.x * (size_t)blockDim.x + threadIdx.x;
  if (tid >= (size_t)N_EDGES * H * C) return;
  int e = (int)(tid / (H * C));
  int i = (int)(tid % (H * C));
  int hh = i / C;
  int s = src[e], d = dst[e];
  float alpha = w[(size_t)e * H + hh] / z[(size_t)d * H + hh];
  atomicAdd(&outp[(size_t)d * (H * C) + i], hfeat[(size_t)s * (H * C) + i] * alpha);
}

// out1 = elu(out1 + b1), in place
__global__ void bias_elu_kernel(float* __restrict__ o, const float* __restrict__ b) {
  size_t tid = blockIdx.x * (size_t)blockDim.x + threadIdx.x;
  if (tid >= (size_t)N_NODES * F1) return;
  float v = o[tid] + b[tid & (F1 - 1)];
  o[tid] = (v > 0.f) ? v : expm1f(v);
}

// out += b2
__global__ void bias_kernel(float* __restrict__ o, const float* __restrict__ b) {
  size_t tid = blockIdx.x * (size_t)blockDim.x + threadIdx.x;
  if (tid >= (size_t)N_NODES * OUTC) return;
  o[tid] += b[tid & (OUTC - 1)];
}

extern "C" void kernel_launch(void* const* d_in, const int* in_sizes, int n_in,
                              void* d_out, int out_size, void* d_ws, size_t ws_size,
                              hipStream_t stream) {
  const float* x      = (const float*)d_in[0];
  const int*   ei     = (const int*)d_in[1];  // [2, E] int32 per harness contract
  const float* W1     = (const float*)d_in[2];
  const float* a1_src = (const float*)d_in[3];
  const float* a1_dst = (const float*)d_in[4];
  const float* b1     = (const float*)d_in[5];
  const float* W2     = (const float*)d_in[6];
  const float* a2_src = (const float*)d_in[7];
  const float* a2_dst = (const float*)d_in[8];
  const float* b2     = (const float*)d_in[9];

  const int* src = ei;
  const int* dst = ei + N_EDGES;
  float* out = (float*)d_out;

  // workspace layout (fp32), ~149 MB total
  float* p = (float*)d_ws;
  float* h1 = p;   p += (size_t)N_NODES * F1;     // 12.8M
  float* out1 = p; p += (size_t)N_NODES * F1;     // 12.8M
  float* as1 = p;  p += (size_t)N_NODES * HEADS;
  float* ad1 = p;  p += (size_t)N_NODES * HEADS;
  float* z1 = p;   p += (size_t)N_NODES * HEADS;
  float* e1 = p;   p += (size_t)N_EDGES * HEADS;  // 6.4M
  float* h2 = p;   p += (size_t)N_NODES * OUTC;   // 3.2M
  float* as2 = p;  p += N_NODES;
  float* ad2 = p;  p += N_NODES;
  float* z2 = p;   p += N_NODES;
  float* e2 = p;   p += N_EDGES;

  // zero the accumulators (ws/out are poisoned 0xAA before every timed call)
  hipMemsetAsync(out1, 0, (size_t)N_NODES * F1 * sizeof(float), stream);
  hipMemsetAsync(z1, 0, (size_t)N_NODES * HEADS * sizeof(float), stream);
  hipMemsetAsync(z2, 0, (size_t)N_NODES * sizeof(float), stream);
  hipMemsetAsync(out, 0, (size_t)N_NODES * OUTC * sizeof(float), stream);

  // ---------------- layer 1 ----------------
  sgemm<64, 64, 16, 4, 4><<<dim3(F1 / 64, (N_NODES + 63) / 64), 256, 0, stream>>>(
      x, W1, h1, N_NODES, F1, INC);
  alpha_kernel<HEADS, HID><<<(N_NODES * HEADS + 255) / 256, 256, 0, stream>>>(
      h1, a1_src, a1_dst, as1, ad1);
  edge_score<HEADS><<<(int)(((size_t)N_EDGES * HEADS + 255) / 256), 256, 0, stream>>>(
      src, dst, as1, ad1, e1, z1);
  edge_aggr<HEADS, HID><<<(int)(((size_t)N_EDGES * F1 + 255) / 256), 256, 0, stream>>>(
      src, dst, h1, e1, z1, out1);
  bias_elu_kernel<<<(int)(((size_t)N_NODES * F1 + 255) / 256), 256, 0, stream>>>(out1, b1);

  // ---------------- layer 2 (H=1, C=64; mean over 1 head == identity) -------
  sgemm<64, 64, 16, 4, 4><<<dim3(OUTC / 64, (N_NODES + 63) / 64), 256, 0, stream>>>(
      out1, W2, h2, N_NODES, OUTC, F1);
  alpha_kernel<1, OUTC><<<(N_NODES + 255) / 256, 256, 0, stream>>>(
      h2, a2_src, a2_dst, as2, ad2);
  edge_score<1><<<(int)(((size_t)N_EDGES + 255) / 256), 256, 0, stream>>>(
      src, dst, as2, ad2, e2, z2);
  edge_aggr<1, OUTC><<<(int)(((size_t)N_EDGES * OUTC + 255) / 256), 256, 0, stream>>>(
      src, dst, h2, e2, z2, out);
  bias_kernel<<<(int)(((size_t)N_NODES * OUTC + 255) / 256), 256, 0, stream>>>(out, b2);
}

// Round 2
// 595.971 us; speedup vs baseline: 1.9556x; 1.9556x over previous
//
#include <hip/hip_runtime.h>
#include <cstdint>
#include <cstddef>

#define N_NODES 50000
#define N_EDGES 800000
#define INC 128
#define HID 32
#define HEADS 8
#define OUTC 64
#define F1 (HEADS * HID) /* 256 */
#define NEG 0.2f

// ---------------------------------------------------------------------------
// Tiled fp32 GEMM: C[M,N] = A[M,K] @ B[K,N]   (N % BN == 0, K % BK == 0)
// BM=BN=64, BK=16, TM=TN=4, 256 threads. fp32 vector-ALU (no fp32 MFMA on CDNA4).
// ---------------------------------------------------------------------------
template <int BM, int BN, int BK, int TM, int TN>
__global__ __launch_bounds__((BM / TM) * (BN / TN)) void sgemm(
    const float* __restrict__ A, const float* __restrict__ B,
    float* __restrict__ C, int M, int N, int K) {
  constexpr int THREADS = (BM / TM) * (BN / TN);
  static_assert(BM * BK / 4 == THREADS, "A tile load mapping");
  static_assert(BK * BN / 4 == THREADS, "B tile load mapping");
  static_assert(TM == 4 && TN == 4, "float4 store path assumes 4x4");

  __shared__ float As[BK][BM + 4];
  __shared__ float Bs[BK][BN];

  const int tid = threadIdx.x;
  const int brow = blockIdx.y, bcol = blockIdx.x;
  const int tr = tid / (BN / TN);
  const int tc = tid % (BN / TN);

  float acc[TM][TN] = {};

  for (int k0 = 0; k0 < K; k0 += BK) {
    {
      int m = tid / (BK / 4);
      int kv = (tid % (BK / 4)) * 4;
      int gm = brow * BM + m;
      float4 v = make_float4(0.f, 0.f, 0.f, 0.f);
      if (gm < M) v = *reinterpret_cast<const float4*>(&A[(size_t)gm * K + k0 + kv]);
      As[kv + 0][m] = v.x;
      As[kv + 1][m] = v.y;
      As[kv + 2][m] = v.z;
      As[kv + 3][m] = v.w;
    }
    {
      int k = tid / (BN / 4);
      int nv = (tid % (BN / 4)) * 4;
      *reinterpret_cast<float4*>(&Bs[k][nv]) =
          *reinterpret_cast<const float4*>(&B[(size_t)(k0 + k) * N + bcol * BN + nv]);
    }
    __syncthreads();
#pragma unroll
    for (int k = 0; k < BK; ++k) {
      float a[TM], b[TN];
#pragma unroll
      for (int i = 0; i < TM; i++) a[i] = As[k][tr * TM + i];
#pragma unroll
      for (int j = 0; j < TN; j++) b[j] = Bs[k][tc * TN + j];
#pragma unroll
      for (int i = 0; i < TM; i++)
#pragma unroll
        for (int j = 0; j < TN; j++) acc[i][j] += a[i] * b[j];
    }
    __syncthreads();
  }

#pragma unroll
  for (int i = 0; i < TM; i++) {
    int gm = brow * BM + tr * TM + i;
    if (gm >= M) break;
    float4 v = make_float4(acc[i][0], acc[i][1], acc[i][2], acc[i][3]);
    *reinterpret_cast<float4*>(&C[(size_t)gm * N + bcol * BN + tc * TN]) = v;
  }
}

// ---------------------------------------------------------------------------
// alpha_s / alpha_d per (node, head)
// ---------------------------------------------------------------------------
template <int H, int C>
__global__ void alpha_kernel(const float* __restrict__ h,
                             const float* __restrict__ a_src,
                             const float* __restrict__ a_dst,
                             float* __restrict__ as, float* __restrict__ ad) {
  int tid = blockIdx.x * blockDim.x + threadIdx.x;
  if (tid >= N_NODES * H) return;
  int n = tid / H, hh = tid % H;
  const float* hp = h + (size_t)n * (H * C) + hh * C;
  const float* sv = a_src + hh * C;
  const float* dv = a_dst + hh * C;
  float s = 0.f, d = 0.f;
#pragma unroll
  for (int k = 0; k < C; k++) {
    float v = hp[k];
    s += v * sv[k];
    d += v * dv[k];
  }
  as[tid] = s;
  ad[tid] = d;
}

// ---------------------------------------------------------------------------
// Per-edge score: w = exp(leakyrelu(as[src] + ad[dst])). No atomics; z is
// computed inline in the gather-aggregation. Max-shift dropped (scores O(+-2),
// softmax shift-invariant).
// ---------------------------------------------------------------------------
template <int H>
__global__ void edge_score(const int* __restrict__ src, const int* __restrict__ dst,
                           const float* __restrict__ as, const float* __restrict__ ad,
                           float* __restrict__ w) {
  size_t tid = blockIdx.x * (size_t)blockDim.x + threadIdx.x;
  if (tid >= (size_t)N_EDGES * H) return;
  int e = (int)(tid / H), hh = (int)(tid % H);
  int s = src[e], d = dst[e];
  float v = as[(size_t)s * H + hh] + ad[(size_t)d * H + hh];
  v = (v >= 0.f) ? v : NEG * v;
  w[tid] = expf(v);
}

// ---------------------------------------------------------------------------
// CSR build: histogram -> 3-phase exclusive scan -> bucket fill (reverse fill
// reusing the count array as cursor; within-bucket order is irrelevant).
// ---------------------------------------------------------------------------
__global__ void deg_count(const int* __restrict__ dst, int* __restrict__ cnt) {
  int e = blockIdx.x * blockDim.x + threadIdx.x;
  if (e < N_EDGES) atomicAdd(&cnt[dst[e]], 1);
}

__global__ void partial_sum(const int* __restrict__ cnt, int* __restrict__ bsum) {
  __shared__ int s[256];
  int i = blockIdx.x * 256 + threadIdx.x;
  s[threadIdx.x] = (i < N_NODES) ? cnt[i] : 0;
  __syncthreads();
  for (int off = 128; off > 0; off >>= 1) {
    if (threadIdx.x < off) s[threadIdx.x] += s[threadIdx.x + off];
    __syncthreads();
  }
  if (threadIdx.x == 0) bsum[blockIdx.x] = s[0];
}

__global__ void scan_bsum(int* __restrict__ bsum, int nb) {
  if (blockIdx.x == 0 && threadIdx.x == 0) {
    int run = 0;
    for (int i = 0; i < nb; i++) { int v = bsum[i]; bsum[i] = run; run += v; }
  }
}

__global__ void block_scan(const int* __restrict__ cnt, const int* __restrict__ bsum,
                           int* __restrict__ rs) {
  __shared__ int s[256];
  int i = blockIdx.x * 256 + threadIdx.x;
  int v = (i < N_NODES) ? cnt[i] : 0;
  s[threadIdx.x] = v;
  __syncthreads();
  for (int off = 1; off < 256; off <<= 1) {
    int t = (threadIdx.x >= off) ? s[threadIdx.x - off] : 0;
    __syncthreads();
    s[threadIdx.x] += t;
    __syncthreads();
  }
  if (i < N_NODES) rs[i] = bsum[blockIdx.x] + s[threadIdx.x] - v;  // exclusive
}

__global__ void fill_csr(const int* __restrict__ src, const int* __restrict__ dst,
                         const int* __restrict__ rs, int* __restrict__ cnt,
                         int* __restrict__ csr_src, int* __restrict__ csr_eid) {
  int e = blockIdx.x * blockDim.x + threadIdx.x;
  if (e >= N_EDGES) return;
  int d = dst[e];
  int pos = atomicSub(&cnt[d], 1) - 1;  // reverse fill; cnt consumed to zero
  int idx = rs[d] + pos;
  csr_src[idx] = src[e];
  csr_eid[idx] = e;
}

// ---------------------------------------------------------------------------
// Gather aggregation, layer 1: one block (256 thr) per dst node, thread i owns
// feature i. out1 = elu( (sum_e h[src]*w) / (sum_e w) + bias ). Zero-degree
// nodes -> elu(bias), matching reference empty-segment semantics.
// ---------------------------------------------------------------------------
__global__ __launch_bounds__(256) void gat_aggr1(
    const int* __restrict__ rs, const int* __restrict__ csr_src,
    const int* __restrict__ csr_eid, const float* __restrict__ h,
    const float* __restrict__ w, const float* __restrict__ bias,
    float* __restrict__ outp) {
  int d = blockIdx.x;
  int i = threadIdx.x;
  int hh = i >> 5;  // head = i / HID
  int beg = rs[d];
  int end = (d == N_NODES - 1) ? N_EDGES : rs[d + 1];
  float acc = 0.f, z = 0.f;
  for (int j = beg; j < end; j++) {
    int s = csr_src[j];
    int e = csr_eid[j];
    float ww = w[(size_t)e * HEADS + hh];
    acc += h[(size_t)s * F1 + i] * ww;
    z += ww;
  }
  float v = (end > beg) ? (acc / z) : 0.f;
  v += bias[i];
  outp[(size_t)d * F1 + i] = (v > 0.f) ? v : expm1f(v);
}

// Layer 2: H=1, C=64. 4 nodes per 256-thread block (one 64-lane wave each).
__global__ __launch_bounds__(256) void gat_aggr2(
    const int* __restrict__ rs, const int* __restrict__ csr_src,
    const int* __restrict__ csr_eid, const float* __restrict__ h,
    const float* __restrict__ w, const float* __restrict__ bias,
    float* __restrict__ outp) {
  int d = blockIdx.x * 4 + (threadIdx.x >> 6);
  int i = threadIdx.x & 63;
  if (d >= N_NODES) return;
  int beg = rs[d];
  int end = (d == N_NODES - 1) ? N_EDGES : rs[d + 1];
  float acc = 0.f, z = 0.f;
  for (int j = beg; j < end; j++) {
    int s = csr_src[j];
    float ww = w[csr_eid[j]];
    acc += h[(size_t)s * OUTC + i] * ww;
    z += ww;
  }
  outp[(size_t)d * OUTC + i] = ((end > beg) ? (acc / z) : 0.f) + bias[i];
}

extern "C" void kernel_launch(void* const* d_in, const int* in_sizes, int n_in,
                              void* d_out, int out_size, void* d_ws, size_t ws_size,
                              hipStream_t stream) {
  const float* x      = (const float*)d_in[0];
  const int*   ei     = (const int*)d_in[1];
  const float* W1     = (const float*)d_in[2];
  const float* a1_src = (const float*)d_in[3];
  const float* a1_dst = (const float*)d_in[4];
  const float* b1     = (const float*)d_in[5];
  const float* W2     = (const float*)d_in[6];
  const float* a2_src = (const float*)d_in[7];
  const float* a2_dst = (const float*)d_in[8];
  const float* b2     = (const float*)d_in[9];

  const int* src = ei;
  const int* dst = ei + N_EDGES;
  float* out = (float*)d_out;

  // workspace layout (4B elems), ~155 MB total
  float* p = (float*)d_ws;
  float* h1 = p;   p += (size_t)N_NODES * F1;     // 12.8M
  float* out1 = p; p += (size_t)N_NODES * F1;     // 12.8M
  float* as1 = p;  p += (size_t)N_NODES * HEADS;
  float* ad1 = p;  p += (size_t)N_NODES * HEADS;
  float* w1 = p;   p += (size_t)N_EDGES * HEADS;  // 6.4M
  float* h2 = p;   p += (size_t)N_NODES * OUTC;   // 3.2M
  float* as2 = p;  p += N_NODES;
  float* ad2 = p;  p += N_NODES;
  float* w2 = p;   p += N_EDGES;
  int* cnt = (int*)p;      p += N_NODES;
  int* rs = (int*)p;       p += N_NODES;
  int* bsum = (int*)p;     p += 256;
  int* csr_src = (int*)p;  p += N_EDGES;
  int* csr_eid = (int*)p;  p += N_EDGES;

  constexpr int NB_SCAN = (N_NODES + 255) / 256;  // 196

  // ---- CSR build (shared by both layers) ----
  hipMemsetAsync(cnt, 0, N_NODES * sizeof(int), stream);
  deg_count<<<(N_EDGES + 255) / 256, 256, 0, stream>>>(dst, cnt);
  partial_sum<<<NB_SCAN, 256, 0, stream>>>(cnt, bsum);
  scan_bsum<<<1, 64, 0, stream>>>(bsum, NB_SCAN);
  block_scan<<<NB_SCAN, 256, 0, stream>>>(cnt, bsum, rs);
  fill_csr<<<(N_EDGES + 255) / 256, 256, 0, stream>>>(src, dst, rs, cnt, csr_src, csr_eid);

  // ---------------- layer 1 ----------------
  sgemm<64, 64, 16, 4, 4><<<dim3(F1 / 64, (N_NODES + 63) / 64), 256, 0, stream>>>(
      x, W1, h1, N_NODES, F1, INC);
  alpha_kernel<HEADS, HID><<<(N_NODES * HEADS + 255) / 256, 256, 0, stream>>>(
      h1, a1_src, a1_dst, as1, ad1);
  edge_score<HEADS><<<(int)(((size_t)N_EDGES * HEADS + 255) / 256), 256, 0, stream>>>(
      src, dst, as1, ad1, w1);
  gat_aggr1<<<N_NODES, 256, 0, stream>>>(rs, csr_src, csr_eid, h1, w1, b1, out1);

  // ---------------- layer 2 ----------------
  sgemm<64, 64, 16, 4, 4><<<dim3(OUTC / 64, (N_NODES + 63) / 64), 256, 0, stream>>>(
      out1, W2, h2, N_NODES, OUTC, F1);
  alpha_kernel<1, OUTC><<<(N_NODES + 255) / 256, 256, 0, stream>>>(
      h2, a2_src, a2_dst, as2, ad2);
  edge_score<1><<<(int)(((size_t)N_EDGES + 255) / 256), 256, 0, stream>>>(
      src, dst, as2, ad2, w2);
  gat_aggr2<<<(N_NODES + 3) / 4, 256, 0, stream>>>(rs, csr_src, csr_eid, h2, w2, b2, out);
}

// Round 3
// 466.421 us; speedup vs baseline: 2.4987x; 1.2778x over previous
//
#include <hip/hip_runtime.h>
#include <cstdint>
#include <cstddef>

#define N_NODES 50000
#define N_EDGES 800000
#define INC 128
#define HID 32
#define HEADS 8
#define OUTC 64
#define F1 (HEADS * HID) /* 256 */
#define NEG 0.2f

typedef unsigned short bf16_t;

__device__ __forceinline__ float bf2f(bf16_t u) {
  union { unsigned int i; float f; } v;
  v.i = ((unsigned int)u) << 16;
  return v.f;
}
__device__ __forceinline__ bf16_t f2bf(float x) {
  union { float f; unsigned int u; } v;
  v.f = x;
  unsigned int r = v.u + 0x7FFFu + ((v.u >> 16) & 1u);  // round-nearest-even
  return (bf16_t)(r >> 16);
}

// ---------------------------------------------------------------------------
// fp32 GEMM, bf16 output: C[M,N] = A[M,K] @ B[K,N]. BM=128 BN=64 BK=16,
// TM=8 TN=4, 256 threads. Vector-ALU fp32 (no fp32 MFMA on CDNA4); fp32
// accumulate, bf16 store (consumers are gathers/dots that tolerate bf16).
// ---------------------------------------------------------------------------
__global__ __launch_bounds__(256) void sgemm_bf16out(
    const float* __restrict__ A, const float* __restrict__ B,
    bf16_t* __restrict__ C, int M, int N, int K) {
  constexpr int BM = 128, BN = 64, BK = 16, TM = 8, TN = 4;
  __shared__ float As[BK][BM + 4];
  __shared__ float Bs[BK][BN];

  const int tid = threadIdx.x;
  const int brow = blockIdx.y, bcol = blockIdx.x;
  const int tr = tid / 16;  // 0..15 -> rows tr*8..tr*8+7
  const int tc = tid % 16;  // 0..15 -> cols tc*4..tc*4+3

  float acc[TM][TN] = {};

  for (int k0 = 0; k0 < K; k0 += BK) {
    // A tile: 128x16 = 512 float4, 2 per thread
#pragma unroll
    for (int r = 0; r < 2; r++) {
      int m = r * 64 + tid / 4;
      int kv = (tid % 4) * 4;
      int gm = brow * BM + m;
      float4 v = make_float4(0.f, 0.f, 0.f, 0.f);
      if (gm < M) v = *reinterpret_cast<const float4*>(&A[(size_t)gm * K + k0 + kv]);
      As[kv + 0][m] = v.x;
      As[kv + 1][m] = v.y;
      As[kv + 2][m] = v.z;
      As[kv + 3][m] = v.w;
    }
    {  // B tile: 16x64 = 256 float4, 1 per thread
      int k = tid / 16;
      int nv = (tid % 16) * 4;
      *reinterpret_cast<float4*>(&Bs[k][nv]) =
          *reinterpret_cast<const float4*>(&B[(size_t)(k0 + k) * N + bcol * BN + nv]);
    }
    __syncthreads();
#pragma unroll
    for (int k = 0; k < BK; ++k) {
      float a[TM], b[TN];
#pragma unroll
      for (int i = 0; i < TM; i++) a[i] = As[k][tr * TM + i];
#pragma unroll
      for (int j = 0; j < TN; j++) b[j] = Bs[k][tc * TN + j];
#pragma unroll
      for (int i = 0; i < TM; i++)
#pragma unroll
        for (int j = 0; j < TN; j++) acc[i][j] += a[i] * b[j];
    }
    __syncthreads();
  }

#pragma unroll
  for (int i = 0; i < TM; i++) {
    int gm = brow * BM + tr * TM + i;
    if (gm >= M) break;
    union { bf16_t h[4]; uint2 u; } pk;
#pragma unroll
    for (int j = 0; j < TN; j++) pk.h[j] = f2bf(acc[i][j]);
    *reinterpret_cast<uint2*>(&C[(size_t)gm * N + bcol * BN + tc * TN]) = pk.u;
  }
}

// ---------------------------------------------------------------------------
// alpha_s / alpha_d per (node, head), bf16 h input
// ---------------------------------------------------------------------------
template <int H, int C>
__global__ void alpha_kernel(const bf16_t* __restrict__ h,
                             const float* __restrict__ a_src,
                             const float* __restrict__ a_dst,
                             float* __restrict__ as, float* __restrict__ ad) {
  int tid = blockIdx.x * blockDim.x + threadIdx.x;
  if (tid >= N_NODES * H) return;
  int n = tid / H, hh = tid % H;
  const bf16_t* hp = h + (size_t)n * (H * C) + hh * C;
  const float* sv = a_src + hh * C;
  const float* dv = a_dst + hh * C;
  float s = 0.f, d = 0.f;
#pragma unroll
  for (int k = 0; k < C; k++) {
    float v = bf2f(hp[k]);
    s += v * sv[k];
    d += v * dv[k];
  }
  as[tid] = s;
  ad[tid] = d;
}

// ---------------------------------------------------------------------------
// Per-edge score: w = exp(leakyrelu(as[src] + ad[dst])). Max-shift dropped:
// scores are O(+-2), softmax is shift-invariant, exp safe in fp32.
// ---------------------------------------------------------------------------
template <int H>
__global__ void edge_score(const int* __restrict__ src, const int* __restrict__ dst,
                           const float* __restrict__ as, const float* __restrict__ ad,
                           float* __restrict__ w) {
  size_t tid = blockIdx.x * (size_t)blockDim.x + threadIdx.x;
  if (tid >= (size_t)N_EDGES * H) return;
  int e = (int)(tid / H), hh = (int)(tid % H);
  int s = src[e], d = dst[e];
  float v = as[(size_t)s * H + hh] + ad[(size_t)d * H + hh];
  v = (v >= 0.f) ? v : NEG * v;
  w[tid] = expf(v);
}

// ---------------------------------------------------------------------------
// CSR build: histogram -> 3-phase exclusive scan -> reverse bucket fill.
// ---------------------------------------------------------------------------
__global__ void deg_count(const int* __restrict__ dst, int* __restrict__ cnt) {
  int e = blockIdx.x * blockDim.x + threadIdx.x;
  if (e < N_EDGES) atomicAdd(&cnt[dst[e]], 1);
}

__global__ void partial_sum(const int* __restrict__ cnt, int* __restrict__ bsum) {
  __shared__ int s[256];
  int i = blockIdx.x * 256 + threadIdx.x;
  s[threadIdx.x] = (i < N_NODES) ? cnt[i] : 0;
  __syncthreads();
  for (int off = 128; off > 0; off >>= 1) {
    if (threadIdx.x < off) s[threadIdx.x] += s[threadIdx.x + off];
    __syncthreads();
  }
  if (threadIdx.x == 0) bsum[blockIdx.x] = s[0];
}

__global__ void scan_bsum(int* __restrict__ bsum, int nb) {
  if (blockIdx.x == 0 && threadIdx.x == 0) {
    int run = 0;
    for (int i = 0; i < nb; i++) { int v = bsum[i]; bsum[i] = run; run += v; }
  }
}

__global__ void block_scan(const int* __restrict__ cnt, const int* __restrict__ bsum,
                           int* __restrict__ rs) {
  __shared__ int s[256];
  int i = blockIdx.x * 256 + threadIdx.x;
  int v = (i < N_NODES) ? cnt[i] : 0;
  s[threadIdx.x] = v;
  __syncthreads();
  for (int off = 1; off < 256; off <<= 1) {
    int t = (threadIdx.x >= off) ? s[threadIdx.x - off] : 0;
    __syncthreads();
    s[threadIdx.x] += t;
    __syncthreads();
  }
  if (i < N_NODES) rs[i] = bsum[blockIdx.x] + s[threadIdx.x] - v;  // exclusive
}

__global__ void fill_csr(const int* __restrict__ src, const int* __restrict__ dst,
                         const int* __restrict__ rs, int* __restrict__ cnt,
                         int* __restrict__ csr_src, int* __restrict__ csr_eid) {
  int e = blockIdx.x * blockDim.x + threadIdx.x;
  if (e >= N_EDGES) return;
  int d = dst[e];
  int pos = atomicSub(&cnt[d], 1) - 1;
  int idx = rs[d] + pos;
  csr_src[idx] = src[e];
  csr_eid[idx] = e;
}

// ---------------------------------------------------------------------------
// Gather aggregation, layer 1: one 256-thr block per dst node, thread i owns
// feature i. out1 = elu( (sum h[src]*w) / (sum w) + bias ). Edge loop
// unrolled x4 to overlap the csr_src -> h dependent-load chain.
// ---------------------------------------------------------------------------
__global__ __launch_bounds__(256) void gat_aggr1(
    const int* __restrict__ rs, const int* __restrict__ csr_src,
    const int* __restrict__ csr_eid, const bf16_t* __restrict__ hb,
    const float* __restrict__ w, const float* __restrict__ bias,
    float* __restrict__ outp) {
  int d = blockIdx.x;
  int i = threadIdx.x;
  int hh = i >> 5;
  int beg = rs[d];
  int end = (d == N_NODES - 1) ? N_EDGES : rs[d + 1];
  float acc = 0.f, z = 0.f;
  int j = beg;
  for (; j + 4 <= end; j += 4) {
    int s0 = csr_src[j], s1 = csr_src[j + 1], s2 = csr_src[j + 2], s3 = csr_src[j + 3];
    int e0 = csr_eid[j], e1 = csr_eid[j + 1], e2 = csr_eid[j + 2], e3 = csr_eid[j + 3];
    float w0 = w[(size_t)e0 * HEADS + hh], w1 = w[(size_t)e1 * HEADS + hh];
    float w2 = w[(size_t)e2 * HEADS + hh], w3 = w[(size_t)e3 * HEADS + hh];
    float h0 = bf2f(hb[(size_t)s0 * F1 + i]), h1 = bf2f(hb[(size_t)s1 * F1 + i]);
    float h2 = bf2f(hb[(size_t)s2 * F1 + i]), h3 = bf2f(hb[(size_t)s3 * F1 + i]);
    acc += h0 * w0 + h1 * w1 + h2 * w2 + h3 * w3;
    z += w0 + w1 + w2 + w3;
  }
  for (; j < end; j++) {
    int s = csr_src[j];
    float ww = w[(size_t)csr_eid[j] * HEADS + hh];
    acc += bf2f(hb[(size_t)s * F1 + i]) * ww;
    z += ww;
  }
  float v = (end > beg) ? (acc / z) : 0.f;
  v += bias[i];
  outp[(size_t)d * F1 + i] = (v > 0.f) ? v : expm1f(v);
}

// Layer 2: H=1, C=64. 4 nodes per 256-thread block (one 64-lane wave each).
__global__ __launch_bounds__(256) void gat_aggr2(
    const int* __restrict__ rs, const int* __restrict__ csr_src,
    const int* __restrict__ csr_eid, const bf16_t* __restrict__ hb,
    const float* __restrict__ w, const float* __restrict__ bias,
    float* __restrict__ outp) {
  int d = blockIdx.x * 4 + (threadIdx.x >> 6);
  int i = threadIdx.x & 63;
  if (d >= N_NODES) return;
  int beg = rs[d];
  int end = (d == N_NODES - 1) ? N_EDGES : rs[d + 1];
  float acc = 0.f, z = 0.f;
  int j = beg;
  for (; j + 4 <= end; j += 4) {
    int s0 = csr_src[j], s1 = csr_src[j + 1], s2 = csr_src[j + 2], s3 = csr_src[j + 3];
    float w0 = w[csr_eid[j]], w1 = w[csr_eid[j + 1]];
    float w2 = w[csr_eid[j + 2]], w3 = w[csr_eid[j + 3]];
    float h0 = bf2f(hb[(size_t)s0 * OUTC + i]), h1 = bf2f(hb[(size_t)s1 * OUTC + i]);
    float h2 = bf2f(hb[(size_t)s2 * OUTC + i]), h3 = bf2f(hb[(size_t)s3 * OUTC + i]);
    acc += h0 * w0 + h1 * w1 + h2 * w2 + h3 * w3;
    z += w0 + w1 + w2 + w3;
  }
  for (; j < end; j++) {
    float ww = w[csr_eid[j]];
    acc += bf2f(hb[(size_t)csr_src[j] * OUTC + i]) * ww;
    z += ww;
  }
  outp[(size_t)d * OUTC + i] = ((end > beg) ? (acc / z) : 0.f) + bias[i];
}

extern "C" void kernel_launch(void* const* d_in, const int* in_sizes, int n_in,
                              void* d_out, int out_size, void* d_ws, size_t ws_size,
                              hipStream_t stream) {
  const float* x      = (const float*)d_in[0];
  const int*   ei     = (const int*)d_in[1];
  const float* W1     = (const float*)d_in[2];
  const float* a1_src = (const float*)d_in[3];
  const float* a1_dst = (const float*)d_in[4];
  const float* b1     = (const float*)d_in[5];
  const float* W2     = (const float*)d_in[6];
  const float* a2_src = (const float*)d_in[7];
  const float* a2_dst = (const float*)d_in[8];
  const float* b2     = (const float*)d_in[9];

  const int* src = ei;
  const int* dst = ei + N_EDGES;
  float* out = (float*)d_out;

  // workspace carve (byte offsets)
  char* base = (char*)d_ws;
  size_t off = 0;
  auto carve = [&](size_t bytes) {
    void* q = base + off;
    off += (bytes + 255) & ~size_t(255);
    return q;
  };
  bf16_t* h1b = (bf16_t*)carve((size_t)N_NODES * F1 * 2);     // 25.6 MB
  float* out1 = (float*)carve((size_t)N_NODES * F1 * 4);      // 51.2 MB
  bf16_t* h2b = (bf16_t*)carve((size_t)N_NODES * OUTC * 2);   // 6.4 MB
  float* as1 = (float*)carve((size_t)N_NODES * HEADS * 4);
  float* ad1 = (float*)carve((size_t)N_NODES * HEADS * 4);
  float* w1 = (float*)carve((size_t)N_EDGES * HEADS * 4);     // 25.6 MB
  float* as2 = (float*)carve((size_t)N_NODES * 4);
  float* ad2 = (float*)carve((size_t)N_NODES * 4);
  float* w2 = (float*)carve((size_t)N_EDGES * 4);
  int* cnt = (int*)carve((size_t)N_NODES * 4);
  int* rs = (int*)carve((size_t)N_NODES * 4);
  int* bsum = (int*)carve(256 * 4);
  int* csr_src = (int*)carve((size_t)N_EDGES * 4);
  int* csr_eid = (int*)carve((size_t)N_EDGES * 4);

  constexpr int NB_SCAN = (N_NODES + 255) / 256;  // 196

  // ---- CSR build (shared by both layers) ----
  hipMemsetAsync(cnt, 0, N_NODES * sizeof(int), stream);
  deg_count<<<(N_EDGES + 255) / 256, 256, 0, stream>>>(dst, cnt);
  partial_sum<<<NB_SCAN, 256, 0, stream>>>(cnt, bsum);
  scan_bsum<<<1, 64, 0, stream>>>(bsum, NB_SCAN);
  block_scan<<<NB_SCAN, 256, 0, stream>>>(cnt, bsum, rs);
  fill_csr<<<(N_EDGES + 255) / 256, 256, 0, stream>>>(src, dst, rs, cnt, csr_src, csr_eid);

  // ---------------- layer 1 ----------------
  sgemm_bf16out<<<dim3(F1 / 64, (N_NODES + 127) / 128), 256, 0, stream>>>(
      x, W1, h1b, N_NODES, F1, INC);
  alpha_kernel<HEADS, HID><<<(N_NODES * HEADS + 255) / 256, 256, 0, stream>>>(
      h1b, a1_src, a1_dst, as1, ad1);
  edge_score<HEADS><<<(int)(((size_t)N_EDGES * HEADS + 255) / 256), 256, 0, stream>>>(
      src, dst, as1, ad1, w1);
  gat_aggr1<<<N_NODES, 256, 0, stream>>>(rs, csr_src, csr_eid, h1b, w1, b1, out1);

  // ---------------- layer 2 ----------------
  sgemm_bf16out<<<dim3(OUTC / 64, (N_NODES + 127) / 128), 256, 0, stream>>>(
      out1, W2, h2b, N_NODES, OUTC, F1);
  alpha_kernel<1, OUTC><<<(N_NODES + 255) / 256, 256, 0, stream>>>(
      h2b, a2_src, a2_dst, as2, ad2);
  edge_score<1><<<(int)(((size_t)N_EDGES + 255) / 256), 256, 0, stream>>>(
      src, dst, as2, ad2, w2);
  gat_aggr2<<<(N_NODES + 3) / 4, 256, 0, stream>>>(rs, csr_src, csr_eid, h2b, w2, b2, out);
}

// Round 4
// 359.505 us; speedup vs baseline: 3.2419x; 1.2974x over previous
//
#include <hip/hip_runtime.h>
#include <cstdint>
#include <cstddef>

#define N_NODES 50000
#define N_EDGES 800000
#define INC 128
#define HID 32
#define HEADS 8
#define OUTC 64
#define F1 (HEADS * HID) /* 256 */
#define NEG 0.2f

typedef unsigned short bf16_t;
typedef __attribute__((ext_vector_type(8))) short bf16x8;   // MFMA A/B frag (4 VGPR)
typedef __attribute__((ext_vector_type(4))) float f32x4;    // MFMA C/D frag

__device__ __forceinline__ float bf2f(bf16_t u) {
  union { unsigned int i; float f; } v;
  v.i = ((unsigned int)u) << 16;
  return v.f;
}
__device__ __forceinline__ bf16_t f2bf(float x) {
  union { float f; unsigned int u; } v;
  v.f = x;
  unsigned int r = v.u + 0x7FFFu + ((v.u >> 16) & 1u);  // RNE
  return (bf16_t)(r >> 16);
}

// ---------------------------------------------------------------------------
// Prep: fp32 -> bf16 feature conversion (x), and W transpose+convert.
// ---------------------------------------------------------------------------
__global__ void f2bf_vec4(const float* __restrict__ in, bf16_t* __restrict__ out,
                          int n4) {
  int t = blockIdx.x * blockDim.x + threadIdx.x;
  if (t >= n4) return;
  float4 v = reinterpret_cast<const float4*>(in)[t];
  union { bf16_t h[4]; uint2 u; } pk;
  pk.h[0] = f2bf(v.x); pk.h[1] = f2bf(v.y); pk.h[2] = f2bf(v.z); pk.h[3] = f2bf(v.w);
  reinterpret_cast<uint2*>(out)[t] = pk.u;
}

// W1 [128,256] -> W1t [256,128] bf16 ; W2 [256,64] -> W2t [64,256] bf16
__global__ void prep_w(const float* __restrict__ W1, const float* __restrict__ W2,
                       bf16_t* __restrict__ W1t, bf16_t* __restrict__ W2t) {
  int t = blockIdx.x * blockDim.x + threadIdx.x;
  if (t < F1 * INC) {
    int n = t / INC, k = t % INC;
    W1t[t] = f2bf(W1[(size_t)k * F1 + n]);
  } else {
    int u = t - F1 * INC;
    if (u < OUTC * F1) {
      int n = u / F1, k = u % F1;
      W2t[u] = f2bf(W2[(size_t)k * OUTC + n]);
    }
  }
}

// ---------------------------------------------------------------------------
// MFMA bf16 GEMM: C[M,N] = A[M,K] @ Bt[N,K]^T, all bf16, fp32 accum.
// Block: 256 thr = 4 waves (2x2), tile 64x64, wave 32x32 via 2x2 16x16x32.
// XOR-swizzled LDS (chunk ^= row&7) -> conflict-free b128 reads/writes.
// Requires K%64==0, N%64==0; M guarded.
// ---------------------------------------------------------------------------
__global__ __launch_bounds__(256) void mfma_gemm(
    const bf16_t* __restrict__ A, const bf16_t* __restrict__ Bt,
    bf16_t* __restrict__ C, int M, int N, int K) {
  constexpr int BM = 64, BN = 64, BK = 64;
  __shared__ bf16_t Asb[BM * BK];  // 8 KB, swizzled
  __shared__ bf16_t Bsb[BN * BK];  // 8 KB, swizzled

  const int tid = threadIdx.x;
  const int wave = tid >> 6, lane = tid & 63;
  const int wm = (wave >> 1) * 32, wn = (wave & 1) * 32;
  const int lr = lane & 15, lq = lane >> 4;
  const int m0 = blockIdx.y * BM, n0 = blockIdx.x * BN;

  f32x4 acc[2][2] = {};

  for (int k0 = 0; k0 < K; k0 += BK) {
    // stage A: 512 chunks of 8 bf16 (16B); 2 per thread
#pragma unroll
    for (int p = 0; p < 2; p++) {
      int id = p * 256 + tid;
      int r = id >> 3, c = id & 7;
      int gm = m0 + r;
      uint4 v = make_uint4(0, 0, 0, 0);
      if (gm < M) v = *reinterpret_cast<const uint4*>(&A[(size_t)gm * K + k0 + c * 8]);
      *reinterpret_cast<uint4*>(&Asb[r * BK + ((c ^ (r & 7)) * 8)]) = v;
    }
#pragma unroll
    for (int p = 0; p < 2; p++) {
      int id = p * 256 + tid;
      int r = id >> 3, c = id & 7;
      uint4 v = *reinterpret_cast<const uint4*>(&Bt[(size_t)(n0 + r) * K + k0 + c * 8]);
      *reinterpret_cast<uint4*>(&Bsb[r * BK + ((c ^ (r & 7)) * 8)]) = v;
    }
    __syncthreads();
#pragma unroll
    for (int kk = 0; kk < 2; kk++) {
      bf16x8 af[2], bfr[2];
#pragma unroll
      for (int mi = 0; mi < 2; mi++) {
        int rr = wm + mi * 16 + lr;
        af[mi] = *reinterpret_cast<const bf16x8*>(
            &Asb[rr * BK + (((kk * 4 + lq) ^ (rr & 7)) * 8)]);
      }
#pragma unroll
      for (int ni = 0; ni < 2; ni++) {
        int rr = wn + ni * 16 + lr;
        bfr[ni] = *reinterpret_cast<const bf16x8*>(
            &Bsb[rr * BK + (((kk * 4 + lq) ^ (rr & 7)) * 8)]);
      }
#pragma unroll
      for (int mi = 0; mi < 2; mi++)
#pragma unroll
        for (int ni = 0; ni < 2; ni++)
          acc[mi][ni] = __builtin_amdgcn_mfma_f32_16x16x32_bf16(
              af[mi], bfr[ni], acc[mi][ni], 0, 0, 0);
    }
    __syncthreads();
  }

  // C/D layout: col = lane&15, row = (lane>>4)*4 + reg  [m89/m91-verified]
#pragma unroll
  for (int mi = 0; mi < 2; mi++)
#pragma unroll
    for (int ni = 0; ni < 2; ni++)
#pragma unroll
      for (int r = 0; r < 4; r++) {
        int gm = m0 + wm + mi * 16 + lq * 4 + r;
        if (gm < M)
          C[(size_t)gm * N + n0 + wn + ni * 16 + lr] = f2bf(acc[mi][ni][r]);
      }
}

// ---------------------------------------------------------------------------
// alpha_s / alpha_d per (node, head), bf16 h input, vectorized 16B loads
// ---------------------------------------------------------------------------
template <int H, int C>
__global__ void alpha_kernel(const bf16_t* __restrict__ h,
                             const float* __restrict__ a_src,
                             const float* __restrict__ a_dst,
                             float* __restrict__ as, float* __restrict__ ad) {
  int tid = blockIdx.x * blockDim.x + threadIdx.x;
  if (tid >= N_NODES * H) return;
  int n = tid / H, hh = tid % H;
  const bf16_t* hp = h + (size_t)n * (H * C) + hh * C;
  const float* sv = a_src + hh * C;
  const float* dv = a_dst + hh * C;
  float s = 0.f, d = 0.f;
#pragma unroll
  for (int k0 = 0; k0 < C; k0 += 8) {
    union { uint4 u; bf16_t e[8]; } ld;
    ld.u = *reinterpret_cast<const uint4*>(&hp[k0]);
#pragma unroll
    for (int j = 0; j < 8; j++) {
      float v = bf2f(ld.e[j]);
      s += v * sv[k0 + j];
      d += v * dv[k0 + j];
    }
  }
  as[tid] = s;
  ad[tid] = d;
}

// ---------------------------------------------------------------------------
// CSR build: histogram -> 3-phase exclusive scan -> reverse bucket fill.
// fill_csr emits csr_src and csr_dst (edge id no longer needed anywhere).
// ---------------------------------------------------------------------------
__global__ void deg_count(const int* __restrict__ dst, int* __restrict__ cnt) {
  int e = blockIdx.x * blockDim.x + threadIdx.x;
  if (e < N_EDGES) atomicAdd(&cnt[dst[e]], 1);
}

__global__ void partial_sum(const int* __restrict__ cnt, int* __restrict__ bsum) {
  __shared__ int s[256];
  int i = blockIdx.x * 256 + threadIdx.x;
  s[threadIdx.x] = (i < N_NODES) ? cnt[i] : 0;
  __syncthreads();
  for (int off = 128; off > 0; off >>= 1) {
    if (threadIdx.x < off) s[threadIdx.x] += s[threadIdx.x + off];
    __syncthreads();
  }
  if (threadIdx.x == 0) bsum[blockIdx.x] = s[0];
}

__global__ void scan_bsum(int* __restrict__ bsum, int nb) {
  if (blockIdx.x == 0 && threadIdx.x == 0) {
    int run = 0;
    for (int i = 0; i < nb; i++) { int v = bsum[i]; bsum[i] = run; run += v; }
  }
}

__global__ void block_scan(const int* __restrict__ cnt, const int* __restrict__ bsum,
                           int* __restrict__ rs) {
  __shared__ int s[256];
  int i = blockIdx.x * 256 + threadIdx.x;
  int v = (i < N_NODES) ? cnt[i] : 0;
  s[threadIdx.x] = v;
  __syncthreads();
  for (int off = 1; off < 256; off <<= 1) {
    int t = (threadIdx.x >= off) ? s[threadIdx.x - off] : 0;
    __syncthreads();
    s[threadIdx.x] += t;
    __syncthreads();
  }
  if (i < N_NODES) rs[i] = bsum[blockIdx.x] + s[threadIdx.x] - v;  // exclusive
}

__global__ void fill_csr(const int* __restrict__ src, const int* __restrict__ dst,
                         const int* __restrict__ rs, int* __restrict__ cnt,
                         int* __restrict__ csr_src, int* __restrict__ csr_dst) {
  int e = blockIdx.x * blockDim.x + threadIdx.x;
  if (e >= N_EDGES) return;
  int d = dst[e];
  int pos = atomicSub(&cnt[d], 1) - 1;
  int idx = rs[d] + pos;
  csr_src[idx] = src[e];
  csr_dst[idx] = d;
}

// ---------------------------------------------------------------------------
// Edge scores in CSR order: wc[j][h] = exp(leakyrelu(as[src_j][h]+ad[dst_j][h]))
// Sequential writes; as/ad gathers hit L2 (<=1.6 MB tables). Max-shift dropped:
// scores O(+-2), softmax shift-invariant, exp safe in fp32.
// ---------------------------------------------------------------------------
__device__ __forceinline__ float lrexp(float v) {
  return expf((v >= 0.f) ? v : NEG * v);
}

__global__ void edge_score_csr8(const int* __restrict__ csr_src,
                                const int* __restrict__ csr_dst,
                                const float* __restrict__ as,
                                const float* __restrict__ ad,
                                float* __restrict__ wc) {
  int j = blockIdx.x * blockDim.x + threadIdx.x;
  if (j >= N_EDGES) return;
  int s = csr_src[j], d = csr_dst[j];
  float4 s0 = *reinterpret_cast<const float4*>(&as[(size_t)s * 8]);
  float4 s1 = *reinterpret_cast<const float4*>(&as[(size_t)s * 8 + 4]);
  float4 d0 = *reinterpret_cast<const float4*>(&ad[(size_t)d * 8]);
  float4 d1 = *reinterpret_cast<const float4*>(&ad[(size_t)d * 8 + 4]);
  float4 o0, o1;
  o0.x = lrexp(s0.x + d0.x); o0.y = lrexp(s0.y + d0.y);
  o0.z = lrexp(s0.z + d0.z); o0.w = lrexp(s0.w + d0.w);
  o1.x = lrexp(s1.x + d1.x); o1.y = lrexp(s1.y + d1.y);
  o1.z = lrexp(s1.z + d1.z); o1.w = lrexp(s1.w + d1.w);
  *reinterpret_cast<float4*>(&wc[(size_t)j * 8]) = o0;
  *reinterpret_cast<float4*>(&wc[(size_t)j * 8 + 4]) = o1;
}

__global__ void edge_score_csr1(const int* __restrict__ csr_src,
                                const int* __restrict__ csr_dst,
                                const float* __restrict__ as,
                                const float* __restrict__ ad,
                                float* __restrict__ wc) {
  int j = blockIdx.x * blockDim.x + threadIdx.x;
  if (j >= N_EDGES) return;
  wc[j] = lrexp(as[csr_src[j]] + ad[csr_dst[j]]);
}

// ---------------------------------------------------------------------------
// Gather aggregation, layer 1: one 128-thr block per dst node, thread owns 2
// consecutive features (ushort2 gather). out1(bf16) = elu(sum(h*w)/sum(w)+b).
// ---------------------------------------------------------------------------
__global__ __launch_bounds__(128) void gat_aggr1(
    const int* __restrict__ rs, const int* __restrict__ csr_src,
    const float* __restrict__ wc, const bf16_t* __restrict__ hb,
    const float* __restrict__ bias, bf16_t* __restrict__ outp) {
  int d = blockIdx.x;
  int t = threadIdx.x;          // feature pair t -> feats 2t, 2t+1
  int hh = t >> 4;              // head = (2t)/32
  int beg = rs[d];
  int end = (d == N_NODES - 1) ? N_EDGES : rs[d + 1];
  float a0 = 0.f, a1 = 0.f, z = 0.f;
  int j = beg;
  for (; j + 4 <= end; j += 4) {
    int s0 = csr_src[j], s1 = csr_src[j + 1], s2 = csr_src[j + 2], s3 = csr_src[j + 3];
    float w0 = wc[(size_t)j * 8 + hh];
    float w1 = wc[(size_t)(j + 1) * 8 + hh];
    float w2 = wc[(size_t)(j + 2) * 8 + hh];
    float w3 = wc[(size_t)(j + 3) * 8 + hh];
    union { unsigned int u; bf16_t e[2]; } h0, h1, h2, h3;
    h0.u = *reinterpret_cast<const unsigned int*>(&hb[(size_t)s0 * F1 + 2 * t]);
    h1.u = *reinterpret_cast<const unsigned int*>(&hb[(size_t)s1 * F1 + 2 * t]);
    h2.u = *reinterpret_cast<const unsigned int*>(&hb[(size_t)s2 * F1 + 2 * t]);
    h3.u = *reinterpret_cast<const unsigned int*>(&hb[(size_t)s3 * F1 + 2 * t]);
    a0 += bf2f(h0.e[0]) * w0 + bf2f(h1.e[0]) * w1 + bf2f(h2.e[0]) * w2 + bf2f(h3.e[0]) * w3;
    a1 += bf2f(h0.e[1]) * w0 + bf2f(h1.e[1]) * w1 + bf2f(h2.e[1]) * w2 + bf2f(h3.e[1]) * w3;
    z += w0 + w1 + w2 + w3;
  }
  for (; j < end; j++) {
    int s = csr_src[j];
    float ww = wc[(size_t)j * 8 + hh];
    union { unsigned int u; bf16_t e[2]; } h0;
    h0.u = *reinterpret_cast<const unsigned int*>(&hb[(size_t)s * F1 + 2 * t]);
    a0 += bf2f(h0.e[0]) * ww;
    a1 += bf2f(h0.e[1]) * ww;
    z += ww;
  }
  float inv = (end > beg) ? (1.f / z) : 0.f;
  float v0 = a0 * inv + bias[2 * t];
  float v1 = a1 * inv + bias[2 * t + 1];
  v0 = (v0 > 0.f) ? v0 : expm1f(v0);
  v1 = (v1 > 0.f) ? v1 : expm1f(v1);
  union { bf16_t e[2]; unsigned int u; } pk;
  pk.e[0] = f2bf(v0); pk.e[1] = f2bf(v1);
  *reinterpret_cast<unsigned int*>(&outp[(size_t)d * F1 + 2 * t]) = pk.u;
}

// Layer 2: H=1, C=64. 4 nodes per 256-thread block (one 64-lane wave each).
__global__ __launch_bounds__(256) void gat_aggr2(
    const int* __restrict__ rs, const int* __restrict__ csr_src,
    const float* __restrict__ wc, const bf16_t* __restrict__ hb,
    const float* __restrict__ bias, float* __restrict__ outp) {
  int d = blockIdx.x * 4 + (threadIdx.x >> 6);
  int i = threadIdx.x & 63;
  if (d >= N_NODES) return;
  int beg = rs[d];
  int end = (d == N_NODES - 1) ? N_EDGES : rs[d + 1];
  float acc = 0.f, z = 0.f;
  int j = beg;
  for (; j + 4 <= end; j += 4) {
    int s0 = csr_src[j], s1 = csr_src[j + 1], s2 = csr_src[j + 2], s3 = csr_src[j + 3];
    float w0 = wc[j], w1 = wc[j + 1], w2 = wc[j + 2], w3 = wc[j + 3];
    float h0 = bf2f(hb[(size_t)s0 * OUTC + i]), h1 = bf2f(hb[(size_t)s1 * OUTC + i]);
    float h2 = bf2f(hb[(size_t)s2 * OUTC + i]), h3 = bf2f(hb[(size_t)s3 * OUTC + i]);
    acc += h0 * w0 + h1 * w1 + h2 * w2 + h3 * w3;
    z += w0 + w1 + w2 + w3;
  }
  for (; j < end; j++) {
    float ww = wc[j];
    acc += bf2f(hb[(size_t)csr_src[j] * OUTC + i]) * ww;
    z += ww;
  }
  outp[(size_t)d * OUTC + i] = ((end > beg) ? (acc / z) : 0.f) + bias[i];
}

extern "C" void kernel_launch(void* const* d_in, const int* in_sizes, int n_in,
                              void* d_out, int out_size, void* d_ws, size_t ws_size,
                              hipStream_t stream) {
  const float* x      = (const float*)d_in[0];
  const int*   ei     = (const int*)d_in[1];
  const float* W1     = (const float*)d_in[2];
  const float* a1_src = (const float*)d_in[3];
  const float* a1_dst = (const float*)d_in[4];
  const float* b1     = (const float*)d_in[5];
  const float* W2     = (const float*)d_in[6];
  const float* a2_src = (const float*)d_in[7];
  const float* a2_dst = (const float*)d_in[8];
  const float* b2     = (const float*)d_in[9];

  const int* src = ei;
  const int* dst = ei + N_EDGES;
  float* out = (float*)d_out;

  // workspace carve (256B-aligned), ~110 MB total
  char* base = (char*)d_ws;
  size_t off = 0;
  auto carve = [&](size_t bytes) {
    void* q = base + off;
    off += (bytes + 255) & ~size_t(255);
    return q;
  };
  bf16_t* xb   = (bf16_t*)carve((size_t)N_NODES * INC * 2);    // 12.8 MB
  bf16_t* h1b  = (bf16_t*)carve((size_t)N_NODES * F1 * 2);     // 25.6 MB
  bf16_t* o1b  = (bf16_t*)carve((size_t)N_NODES * F1 * 2);     // 25.6 MB
  bf16_t* h2b  = (bf16_t*)carve((size_t)N_NODES * OUTC * 2);   // 6.4 MB
  bf16_t* W1t  = (bf16_t*)carve((size_t)F1 * INC * 2);
  bf16_t* W2t  = (bf16_t*)carve((size_t)OUTC * F1 * 2);
  float* as1 = (float*)carve((size_t)N_NODES * HEADS * 4);
  float* ad1 = (float*)carve((size_t)N_NODES * HEADS * 4);
  float* wc1 = (float*)carve((size_t)N_EDGES * HEADS * 4);     // 25.6 MB
  float* as2 = (float*)carve((size_t)N_NODES * 4);
  float* ad2 = (float*)carve((size_t)N_NODES * 4);
  float* wc2 = (float*)carve((size_t)N_EDGES * 4);
  int* cnt = (int*)carve((size_t)N_NODES * 4);
  int* rs = (int*)carve((size_t)N_NODES * 4);
  int* bsum = (int*)carve(256 * 4);
  int* csr_src = (int*)carve((size_t)N_EDGES * 4);
  int* csr_dst = (int*)carve((size_t)N_EDGES * 4);

  constexpr int NB_SCAN = (N_NODES + 255) / 256;  // 196

  // ---- prep: bf16 conversions ----
  f2bf_vec4<<<(N_NODES * INC / 4 + 255) / 256, 256, 0, stream>>>(x, xb, N_NODES * INC / 4);
  prep_w<<<(F1 * INC + OUTC * F1 + 255) / 256, 256, 0, stream>>>(W1, W2, W1t, W2t);

  // ---- CSR build (shared by both layers) ----
  hipMemsetAsync(cnt, 0, N_NODES * sizeof(int), stream);
  deg_count<<<(N_EDGES + 255) / 256, 256, 0, stream>>>(dst, cnt);
  partial_sum<<<NB_SCAN, 256, 0, stream>>>(cnt, bsum);
  scan_bsum<<<1, 64, 0, stream>>>(bsum, NB_SCAN);
  block_scan<<<NB_SCAN, 256, 0, stream>>>(cnt, bsum, rs);
  fill_csr<<<(N_EDGES + 255) / 256, 256, 0, stream>>>(src, dst, rs, cnt, csr_src, csr_dst);

  // ---------------- layer 1 ----------------
  mfma_gemm<<<dim3(F1 / 64, (N_NODES + 63) / 64), 256, 0, stream>>>(
      xb, W1t, h1b, N_NODES, F1, INC);
  alpha_kernel<HEADS, HID><<<(N_NODES * HEADS + 255) / 256, 256, 0, stream>>>(
      h1b, a1_src, a1_dst, as1, ad1);
  edge_score_csr8<<<(N_EDGES + 255) / 256, 256, 0, stream>>>(
      csr_src, csr_dst, as1, ad1, wc1);
  gat_aggr1<<<N_NODES, 128, 0, stream>>>(rs, csr_src, wc1, h1b, b1, o1b);

  // ---------------- layer 2 ----------------
  mfma_gemm<<<dim3(OUTC / 64, (N_NODES + 63) / 64), 256, 0, stream>>>(
      o1b, W2t, h2b, N_NODES, OUTC, F1);
  alpha_kernel<1, OUTC><<<(N_NODES + 255) / 256, 256, 0, stream>>>(
      h2b, a2_src, a2_dst, as2, ad2);
  edge_score_csr1<<<(N_EDGES + 255) / 256, 256, 0, stream>>>(
      csr_src, csr_dst, as2, ad2, wc2);
  gat_aggr2<<<(N_NODES + 3) / 4, 256, 0, stream>>>(rs, csr_src, wc2, h2b, b2, out);
}

// Round 5
// 323.003 us; speedup vs baseline: 3.6082x; 1.1130x over previous
//
#include <hip/hip_runtime.h>
#include <cstdint>
#include <cstddef>

#define N_NODES 50000
#define N_EDGES 800000
#define INC 128
#define HID 32
#define HEADS 8
#define OUTC 64
#define F1 (HEADS * HID) /* 256 */
#define NEG 0.2f

typedef unsigned short bf16_t;
typedef __attribute__((ext_vector_type(8))) short bf16x8;   // MFMA A/B frag (4 VGPR)
typedef __attribute__((ext_vector_type(4))) float f32x4;    // MFMA C/D frag

__device__ __forceinline__ float bf2f(bf16_t u) {
  union { unsigned int i; float f; } v;
  v.i = ((unsigned int)u) << 16;
  return v.f;
}
__device__ __forceinline__ bf16_t f2bf(float x) {
  union { float f; unsigned int u; } v;
  v.f = x;
  unsigned int r = v.u + 0x7FFFu + ((v.u >> 16) & 1u);  // RNE
  return (bf16_t)(r >> 16);
}
__device__ __forceinline__ float lrexp(float v) {
  return expf((v >= 0.f) ? v : NEG * v);
}

// ---------------------------------------------------------------------------
// Fused prep: x fp32->bf16 (vec4), W1/W2 transpose+convert, cnt zero-fill.
// ---------------------------------------------------------------------------
__global__ void prep_all(const float* __restrict__ x, const float* __restrict__ W1,
                         const float* __restrict__ W2, bf16_t* __restrict__ xb,
                         bf16_t* __restrict__ W1t, bf16_t* __restrict__ W2t,
                         int* __restrict__ cnt) {
  int t = blockIdx.x * blockDim.x + threadIdx.x;
  constexpr int NX = N_NODES * INC / 4;  // 1.6M float4 chunks
  if (t < N_NODES) cnt[t] = 0;
  if (t < NX) {
    float4 v = reinterpret_cast<const float4*>(x)[t];
    union { bf16_t h[4]; uint2 u; } pk;
    pk.h[0] = f2bf(v.x); pk.h[1] = f2bf(v.y); pk.h[2] = f2bf(v.z); pk.h[3] = f2bf(v.w);
    reinterpret_cast<uint2*>(xb)[t] = pk.u;
  } else {
    int u = t - NX;
    if (u < F1 * INC) {
      int n = u / INC, k = u % INC;
      W1t[u] = f2bf(W1[(size_t)k * F1 + n]);
    } else {
      u -= F1 * INC;
      if (u < OUTC * F1) {
        int n = u / F1, k = u % F1;
        W2t[u] = f2bf(W2[(size_t)k * OUTC + n]);
      }
    }
  }
}

// ---------------------------------------------------------------------------
// MFMA bf16 GEMM: C[M,N] = A[M,K] @ Bt[N,K]^T, all bf16, fp32 accum.
// 256 thr = 4 waves (2x2), tile 64x64, wave 32x32 via 2x2 16x16x32.
// XOR-swizzled LDS -> conflict-free b128. K%64==0, N%64==0; M guarded.
// ---------------------------------------------------------------------------
__global__ __launch_bounds__(256) void mfma_gemm(
    const bf16_t* __restrict__ A, const bf16_t* __restrict__ Bt,
    bf16_t* __restrict__ C, int M, int N, int K) {
  constexpr int BM = 64, BN = 64, BK = 64;
  __shared__ bf16_t Asb[BM * BK];
  __shared__ bf16_t Bsb[BN * BK];

  const int tid = threadIdx.x;
  const int wave = tid >> 6, lane = tid & 63;
  const int wm = (wave >> 1) * 32, wn = (wave & 1) * 32;
  const int lr = lane & 15, lq = lane >> 4;
  const int m0 = blockIdx.y * BM, n0 = blockIdx.x * BN;

  f32x4 acc[2][2] = {};

  for (int k0 = 0; k0 < K; k0 += BK) {
#pragma unroll
    for (int p = 0; p < 2; p++) {
      int id = p * 256 + tid;
      int r = id >> 3, c = id & 7;
      int gm = m0 + r;
      uint4 v = make_uint4(0, 0, 0, 0);
      if (gm < M) v = *reinterpret_cast<const uint4*>(&A[(size_t)gm * K + k0 + c * 8]);
      *reinterpret_cast<uint4*>(&Asb[r * BK + ((c ^ (r & 7)) * 8)]) = v;
    }
#pragma unroll
    for (int p = 0; p < 2; p++) {
      int id = p * 256 + tid;
      int r = id >> 3, c = id & 7;
      uint4 v = *reinterpret_cast<const uint4*>(&Bt[(size_t)(n0 + r) * K + k0 + c * 8]);
      *reinterpret_cast<uint4*>(&Bsb[r * BK + ((c ^ (r & 7)) * 8)]) = v;
    }
    __syncthreads();
#pragma unroll
    for (int kk = 0; kk < 2; kk++) {
      bf16x8 af[2], bfr[2];
#pragma unroll
      for (int mi = 0; mi < 2; mi++) {
        int rr = wm + mi * 16 + lr;
        af[mi] = *reinterpret_cast<const bf16x8*>(
            &Asb[rr * BK + (((kk * 4 + lq) ^ (rr & 7)) * 8)]);
      }
#pragma unroll
      for (int ni = 0; ni < 2; ni++) {
        int rr = wn + ni * 16 + lr;
        bfr[ni] = *reinterpret_cast<const bf16x8*>(
            &Bsb[rr * BK + (((kk * 4 + lq) ^ (rr & 7)) * 8)]);
      }
#pragma unroll
      for (int mi = 0; mi < 2; mi++)
#pragma unroll
        for (int ni = 0; ni < 2; ni++)
          acc[mi][ni] = __builtin_amdgcn_mfma_f32_16x16x32_bf16(
              af[mi], bfr[ni], acc[mi][ni], 0, 0, 0);
    }
    __syncthreads();
  }

  // C/D: col = lane&15, row = (lane>>4)*4 + reg
#pragma unroll
  for (int mi = 0; mi < 2; mi++)
#pragma unroll
    for (int ni = 0; ni < 2; ni++)
#pragma unroll
      for (int r = 0; r < 4; r++) {
        int gm = m0 + wm + mi * 16 + lq * 4 + r;
        if (gm < M)
          C[(size_t)gm * N + n0 + wn + ni * 16 + lr] = f2bf(acc[mi][ni][r]);
      }
}

// ---------------------------------------------------------------------------
// alpha_s / alpha_d per (node, head), bf16 h input, 16B loads
// ---------------------------------------------------------------------------
template <int H, int C>
__global__ void alpha_kernel(const bf16_t* __restrict__ h,
                             const float* __restrict__ a_src,
                             const float* __restrict__ a_dst,
                             float* __restrict__ as, float* __restrict__ ad) {
  int tid = blockIdx.x * blockDim.x + threadIdx.x;
  if (tid >= N_NODES * H) return;
  int n = tid / H, hh = tid % H;
  const bf16_t* hp = h + (size_t)n * (H * C) + hh * C;
  const float* sv = a_src + hh * C;
  const float* dv = a_dst + hh * C;
  float s = 0.f, d = 0.f;
#pragma unroll
  for (int k0 = 0; k0 < C; k0 += 8) {
    union { uint4 u; bf16_t e[8]; } ld;
    ld.u = *reinterpret_cast<const uint4*>(&hp[k0]);
#pragma unroll
    for (int j = 0; j < 8; j++) {
      float v = bf2f(ld.e[j]);
      s += v * sv[k0 + j];
      d += v * dv[k0 + j];
    }
  }
  as[tid] = s;
  ad[tid] = d;
}

// ---------------------------------------------------------------------------
// CSR build: histogram -> parallel scan -> reverse bucket fill.
// ---------------------------------------------------------------------------
__global__ void deg_count(const int* __restrict__ dst, int* __restrict__ cnt) {
  int e = blockIdx.x * blockDim.x + threadIdx.x;
  if (e < N_EDGES) atomicAdd(&cnt[dst[e]], 1);
}

__global__ void partial_sum(const int* __restrict__ cnt, int* __restrict__ bsum) {
  __shared__ int s[256];
  int i = blockIdx.x * 256 + threadIdx.x;
  s[threadIdx.x] = (i < N_NODES) ? cnt[i] : 0;
  __syncthreads();
  for (int off = 128; off > 0; off >>= 1) {
    if (threadIdx.x < off) s[threadIdx.x] += s[threadIdx.x + off];
    __syncthreads();
  }
  if (threadIdx.x == 0) bsum[blockIdx.x] = s[0];
}

// Parallel exclusive scan of the (<=256) block sums in one 256-thread block.
// (Replaces the serial 1-thread loop: 196 dependent global round-trips.)
__global__ void scan_bsum(int* __restrict__ bsum, int nb) {
  __shared__ int s[256];
  int t = threadIdx.x;
  int orig = (t < nb) ? bsum[t] : 0;
  s[t] = orig;
  __syncthreads();
  for (int off = 1; off < 256; off <<= 1) {
    int v = (t >= off) ? s[t - off] : 0;
    __syncthreads();
    s[t] += v;
    __syncthreads();
  }
  if (t < nb) bsum[t] = s[t] - orig;  // exclusive
}

__global__ void block_scan(const int* __restrict__ cnt, const int* __restrict__ bsum,
                           int* __restrict__ rs) {
  __shared__ int s[256];
  int i = blockIdx.x * 256 + threadIdx.x;
  int v = (i < N_NODES) ? cnt[i] : 0;
  s[threadIdx.x] = v;
  __syncthreads();
  for (int off = 1; off < 256; off <<= 1) {
    int t = (threadIdx.x >= off) ? s[threadIdx.x - off] : 0;
    __syncthreads();
    s[threadIdx.x] += t;
    __syncthreads();
  }
  if (i < N_NODES) rs[i] = bsum[blockIdx.x] + s[threadIdx.x] - v;  // exclusive
}

__global__ void fill_csr(const int* __restrict__ src, const int* __restrict__ dst,
                         const int* __restrict__ rs, int* __restrict__ cnt,
                         int* __restrict__ csr_src) {
  int e = blockIdx.x * blockDim.x + threadIdx.x;
  if (e >= N_EDGES) return;
  int d = dst[e];
  int pos = atomicSub(&cnt[d], 1) - 1;
  csr_src[rs[d] + pos] = src[e];
}

// ---------------------------------------------------------------------------
// Fused score+aggregate, layer 1. One wave per dst node (4 waves/block), lane
// owns 4 consecutive feats (uint2 gather). Scores computed wave-parallel in
// chunks of 8 edges x 8 heads, broadcast via __shfl (no LDS, no wc stream).
// out1(bf16) = elu(sum(h*w)/sum(w) + bias). Max-shift dropped (scores O(+-2)).
// ---------------------------------------------------------------------------
__global__ __launch_bounds__(256) void gat_aggr1(
    const int* __restrict__ rs, const int* __restrict__ csr_src,
    const float* __restrict__ as, const float* __restrict__ ad,
    const bf16_t* __restrict__ hb, const float* __restrict__ bias,
    bf16_t* __restrict__ outp) {
  int d = blockIdx.x * 4 + (threadIdx.x >> 6);
  int lane = threadIdx.x & 63;
  if (d >= N_NODES) return;
  int beg = rs[d];
  int end = (d == N_NODES - 1) ? N_EDGES : rs[d + 1];
  const int sh = lane & 7;   // scorer head (lane scores edge cb+(lane>>3), head sh)
  const int ah = lane >> 3;  // aggregation head for feats 4*lane..4*lane+3
  float ad_h = ad[(size_t)d * 8 + sh];
  float a0 = 0.f, a1 = 0.f, a2 = 0.f, a3 = 0.f, z = 0.f;

  auto step = [&](int e, float w_reg, int s_reg) {
    float wv = __shfl(w_reg, (e << 3) | ah);
    int sv = __shfl(s_reg, e << 3);
    union { uint2 u; bf16_t h[4]; } ld;
    ld.u = *reinterpret_cast<const uint2*>(&hb[(size_t)sv * F1 + 4 * lane]);
    a0 += bf2f(ld.h[0]) * wv;
    a1 += bf2f(ld.h[1]) * wv;
    a2 += bf2f(ld.h[2]) * wv;
    a3 += bf2f(ld.h[3]) * wv;
    z += wv;
  };

  for (int cb = beg; cb < end; cb += 8) {
    int ei = cb + (lane >> 3);
    int s_reg = csr_src[(ei < end) ? ei : (end - 1)];
    float w_reg = (ei < end) ? lrexp(as[(size_t)s_reg * 8 + sh] + ad_h) : 0.f;
    int cnt = end - cb;
    if (cnt >= 8) {
#pragma unroll
      for (int e = 0; e < 8; e++) step(e, w_reg, s_reg);
    } else {
      for (int e = 0; e < cnt; e++) step(e, w_reg, s_reg);
    }
  }

  float inv = (end > beg) ? (1.f / z) : 0.f;
  float v0 = a0 * inv + bias[4 * lane + 0];
  float v1 = a1 * inv + bias[4 * lane + 1];
  float v2 = a2 * inv + bias[4 * lane + 2];
  float v3 = a3 * inv + bias[4 * lane + 3];
  v0 = (v0 > 0.f) ? v0 : expm1f(v0);
  v1 = (v1 > 0.f) ? v1 : expm1f(v1);
  v2 = (v2 > 0.f) ? v2 : expm1f(v2);
  v3 = (v3 > 0.f) ? v3 : expm1f(v3);
  union { bf16_t h[4]; uint2 u; } pk;
  pk.h[0] = f2bf(v0); pk.h[1] = f2bf(v1); pk.h[2] = f2bf(v2); pk.h[3] = f2bf(v3);
  *reinterpret_cast<uint2*>(&outp[(size_t)d * F1 + 4 * lane]) = pk.u;
}

// ---------------------------------------------------------------------------
// Fused score+aggregate, layer 2 (H=1, C=64). One wave per dst node, lane owns
// 1 feat. Scores for up to 64 edges computed in one wave-parallel phase.
// ---------------------------------------------------------------------------
__global__ __launch_bounds__(256) void gat_aggr2(
    const int* __restrict__ rs, const int* __restrict__ csr_src,
    const float* __restrict__ as, const float* __restrict__ ad,
    const bf16_t* __restrict__ hb, const float* __restrict__ bias,
    float* __restrict__ outp) {
  int d = blockIdx.x * 4 + (threadIdx.x >> 6);
  int lane = threadIdx.x & 63;
  if (d >= N_NODES) return;
  int beg = rs[d];
  int end = (d == N_NODES - 1) ? N_EDGES : rs[d + 1];
  float ad_d = ad[d];
  float acc = 0.f, z = 0.f;

  auto step = [&](int e, float w_reg, int s_reg) {
    float wv = __shfl(w_reg, e);
    int sv = __shfl(s_reg, e);
    acc += bf2f(hb[(size_t)sv * OUTC + lane]) * wv;
    z += wv;
  };

  for (int cb = beg; cb < end; cb += 64) {
    int ei = cb + lane;
    int s_reg = csr_src[(ei < end) ? ei : (end - 1)];
    float w_reg = (ei < end) ? lrexp(as[s_reg] + ad_d) : 0.f;
    int cnt = end - cb;
    if (cnt > 64) cnt = 64;
    int e = 0;
    for (; e + 4 <= cnt; e += 4) {
      step(e + 0, w_reg, s_reg);
      step(e + 1, w_reg, s_reg);
      step(e + 2, w_reg, s_reg);
      step(e + 3, w_reg, s_reg);
    }
    for (; e < cnt; e++) step(e, w_reg, s_reg);
  }

  outp[(size_t)d * OUTC + lane] = ((end > beg) ? (acc / z) : 0.f) + bias[lane];
}

extern "C" void kernel_launch(void* const* d_in, const int* in_sizes, int n_in,
                              void* d_out, int out_size, void* d_ws, size_t ws_size,
                              hipStream_t stream) {
  const float* x      = (const float*)d_in[0];
  const int*   ei     = (const int*)d_in[1];
  const float* W1     = (const float*)d_in[2];
  const float* a1_src = (const float*)d_in[3];
  const float* a1_dst = (const float*)d_in[4];
  const float* b1     = (const float*)d_in[5];
  const float* W2     = (const float*)d_in[6];
  const float* a2_src = (const float*)d_in[7];
  const float* a2_dst = (const float*)d_in[8];
  const float* b2     = (const float*)d_in[9];

  const int* src = ei;
  const int* dst = ei + N_EDGES;
  float* out = (float*)d_out;

  char* base = (char*)d_ws;
  size_t off = 0;
  auto carve = [&](size_t bytes) {
    void* q = base + off;
    off += (bytes + 255) & ~size_t(255);
    return q;
  };
  bf16_t* xb   = (bf16_t*)carve((size_t)N_NODES * INC * 2);    // 12.8 MB
  bf16_t* h1b  = (bf16_t*)carve((size_t)N_NODES * F1 * 2);     // 25.6 MB
  bf16_t* o1b  = (bf16_t*)carve((size_t)N_NODES * F1 * 2);     // 25.6 MB
  bf16_t* h2b  = (bf16_t*)carve((size_t)N_NODES * OUTC * 2);   // 6.4 MB
  bf16_t* W1t  = (bf16_t*)carve((size_t)F1 * INC * 2);
  bf16_t* W2t  = (bf16_t*)carve((size_t)OUTC * F1 * 2);
  float* as1 = (float*)carve((size_t)N_NODES * HEADS * 4);
  float* ad1 = (float*)carve((size_t)N_NODES * HEADS * 4);
  float* as2 = (float*)carve((size_t)N_NODES * 4);
  float* ad2 = (float*)carve((size_t)N_NODES * 4);
  int* cnt = (int*)carve((size_t)N_NODES * 4);
  int* rs = (int*)carve((size_t)N_NODES * 4);
  int* bsum = (int*)carve(256 * 4);
  int* csr_src = (int*)carve((size_t)N_EDGES * 4);

  constexpr int NB_SCAN = (N_NODES + 255) / 256;  // 196
  constexpr int NPREP = N_NODES * INC / 4 + F1 * INC + OUTC * F1;

  // ---- prep (x->bf16, W transposes, cnt=0) ----
  prep_all<<<(NPREP + 255) / 256, 256, 0, stream>>>(x, W1, W2, xb, W1t, W2t, cnt);

  // ---- CSR build ----
  deg_count<<<(N_EDGES + 255) / 256, 256, 0, stream>>>(dst, cnt);
  partial_sum<<<NB_SCAN, 256, 0, stream>>>(cnt, bsum);
  scan_bsum<<<1, 256, 0, stream>>>(bsum, NB_SCAN);
  block_scan<<<NB_SCAN, 256, 0, stream>>>(cnt, bsum, rs);
  fill_csr<<<(N_EDGES + 255) / 256, 256, 0, stream>>>(src, dst, rs, cnt, csr_src);

  // ---------------- layer 1 ----------------
  mfma_gemm<<<dim3(F1 / 64, (N_NODES + 63) / 64), 256, 0, stream>>>(
      xb, W1t, h1b, N_NODES, F1, INC);
  alpha_kernel<HEADS, HID><<<(N_NODES * HEADS + 255) / 256, 256, 0, stream>>>(
      h1b, a1_src, a1_dst, as1, ad1);
  gat_aggr1<<<(N_NODES + 3) / 4, 256, 0, stream>>>(rs, csr_src, as1, ad1, h1b, b1, o1b);

  // ---------------- layer 2 ----------------
  mfma_gemm<<<dim3(OUTC / 64, (N_NODES + 63) / 64), 256, 0, stream>>>(
      o1b, W2t, h2b, N_NODES, OUTC, F1);
  alpha_kernel<1, OUTC><<<(N_NODES + 255) / 256, 256, 0, stream>>>(
      h2b, a2_src, a2_dst, as2, ad2);
  gat_aggr2<<<(N_NODES + 3) / 4, 256, 0, stream>>>(rs, csr_src, as2, ad2, h2b, b2, out);
}

// Round 6
// 317.950 us; speedup vs baseline: 3.6656x; 1.0159x over previous
//
#include <hip/hip_runtime.h>
#include <cstdint>
#include <cstddef>

#define N_NODES 50000
#define N_EDGES 800000
#define INC 128
#define HID 32
#define HEADS 8
#define OUTC 64
#define F1 (HEADS * HID) /* 256 */
#define NEG 0.2f

typedef unsigned short bf16_t;
typedef __attribute__((ext_vector_type(8))) short bf16x8;   // MFMA A/B frag (4 VGPR)
typedef __attribute__((ext_vector_type(4))) float f32x4;    // MFMA C/D frag

__device__ __forceinline__ float bf2f(bf16_t u) {
  union { unsigned int i; float f; } v;
  v.i = ((unsigned int)u) << 16;
  return v.f;
}
__device__ __forceinline__ bf16_t f2bf(float x) {
  union { float f; unsigned int u; } v;
  v.f = x;
  unsigned int r = v.u + 0x7FFFu + ((v.u >> 16) & 1u);  // RNE
  return (bf16_t)(r >> 16);
}
__device__ __forceinline__ float lrexp(float v) {
  return expf((v >= 0.f) ? v : NEG * v);
}

// ---------------------------------------------------------------------------
// Prep: W1/W2 transpose+convert to bf16, cnt zero-fill. (x is consumed fp32
// directly by the fused GEMM staging now.)
// ---------------------------------------------------------------------------
__global__ void prep_w(const float* __restrict__ W1, const float* __restrict__ W2,
                       bf16_t* __restrict__ W1t, bf16_t* __restrict__ W2t,
                       int* __restrict__ cnt) {
  int t = blockIdx.x * blockDim.x + threadIdx.x;
  if (t < N_NODES) cnt[t] = 0;
  if (t < F1 * INC) {
    int n = t / INC, k = t % INC;
    W1t[t] = f2bf(W1[(size_t)k * F1 + n]);
  } else {
    int u = t - F1 * INC;
    if (u < OUTC * F1) {
      int n = u / F1, k = u % F1;
      W2t[u] = f2bf(W2[(size_t)k * OUTC + n]);
    }
  }
}

// ---------------------------------------------------------------------------
// MFMA bf16 GEMM + fused alpha epilogue.
// C[M,N] = A[M,K] @ Bt[N,K]^T; AF32: A is fp32 (converted during staging).
// 256 thr = 4 waves (2x2), tile 64x64, wave 32x32 via 2x2 16x16x32,
// XOR-swizzled LDS. Epilogue: C tile -> LDS fp32; per-row dots with
// a_src/a_dst give as/ad (HPT heads per 64-col tile; HTOT total heads).
// ---------------------------------------------------------------------------
template <bool AF32, int HPT, int HTOT>
__global__ __launch_bounds__(256) void mfma_gemm_fused(
    const void* __restrict__ Av, const bf16_t* __restrict__ Bt,
    bf16_t* __restrict__ C, const float* __restrict__ a_src,
    const float* __restrict__ a_dst, float* __restrict__ as,
    float* __restrict__ ad, int M, int N, int K) {
  constexpr int BM = 64, BN = 64, BK = 64;
  __shared__ union SM {
    struct { bf16_t A[BM * BK]; bf16_t B[BN * BK]; } st;
    struct { float ct[64][65]; float pr[64][4]; } epi;
  } sm;

  const int tid = threadIdx.x;
  const int wave = tid >> 6, lane = tid & 63;
  const int wm = (wave >> 1) * 32, wn = (wave & 1) * 32;
  const int lr = lane & 15, lq = lane >> 4;
  const int m0 = blockIdx.y * BM, n0 = blockIdx.x * BN;
  const float* A32 = (const float*)Av;
  const bf16_t* A16 = (const bf16_t*)Av;

  f32x4 acc[2][2] = {};

  for (int k0 = 0; k0 < K; k0 += BK) {
#pragma unroll
    for (int p = 0; p < 2; p++) {
      int id = p * 256 + tid;
      int r = id >> 3, c = id & 7;
      int gm = m0 + r;
      uint4 v = make_uint4(0, 0, 0, 0);
      if constexpr (AF32) {
        if (gm < M) {
          const float4* ap =
              reinterpret_cast<const float4*>(&A32[(size_t)gm * K + k0 + c * 8]);
          float4 v0 = ap[0], v1 = ap[1];
          union { bf16_t h[8]; uint4 u; } pk;
          pk.h[0] = f2bf(v0.x); pk.h[1] = f2bf(v0.y);
          pk.h[2] = f2bf(v0.z); pk.h[3] = f2bf(v0.w);
          pk.h[4] = f2bf(v1.x); pk.h[5] = f2bf(v1.y);
          pk.h[6] = f2bf(v1.z); pk.h[7] = f2bf(v1.w);
          v = pk.u;
        }
      } else {
        if (gm < M) v = *reinterpret_cast<const uint4*>(&A16[(size_t)gm * K + k0 + c * 8]);
      }
      *reinterpret_cast<uint4*>(&sm.st.A[r * BK + ((c ^ (r & 7)) * 8)]) = v;
    }
#pragma unroll
    for (int p = 0; p < 2; p++) {
      int id = p * 256 + tid;
      int r = id >> 3, c = id & 7;
      uint4 v = *reinterpret_cast<const uint4*>(&Bt[(size_t)(n0 + r) * K + k0 + c * 8]);
      *reinterpret_cast<uint4*>(&sm.st.B[r * BK + ((c ^ (r & 7)) * 8)]) = v;
    }
    __syncthreads();
#pragma unroll
    for (int kk = 0; kk < 2; kk++) {
      bf16x8 af[2], bfr[2];
#pragma unroll
      for (int mi = 0; mi < 2; mi++) {
        int rr = wm + mi * 16 + lr;
        af[mi] = *reinterpret_cast<const bf16x8*>(
            &sm.st.A[rr * BK + (((kk * 4 + lq) ^ (rr & 7)) * 8)]);
      }
#pragma unroll
      for (int ni = 0; ni < 2; ni++) {
        int rr = wn + ni * 16 + lr;
        bfr[ni] = *reinterpret_cast<const bf16x8*>(
            &sm.st.B[rr * BK + (((kk * 4 + lq) ^ (rr & 7)) * 8)]);
      }
#pragma unroll
      for (int mi = 0; mi < 2; mi++)
#pragma unroll
        for (int ni = 0; ni < 2; ni++)
          acc[mi][ni] = __builtin_amdgcn_mfma_f32_16x16x32_bf16(
              af[mi], bfr[ni], acc[mi][ni], 0, 0, 0);
    }
    __syncthreads();
  }

  // stage C tile (fp32) to LDS for alpha dots
#pragma unroll
  for (int mi = 0; mi < 2; mi++)
#pragma unroll
    for (int ni = 0; ni < 2; ni++)
#pragma unroll
      for (int r = 0; r < 4; r++)
        sm.epi.ct[wm + mi * 16 + lq * 4 + r][wn + ni * 16 + lr] = acc[mi][ni][r];
  __syncthreads();

  // global C stores (bf16) from registers; C/D: col=lane&15, row=(lane>>4)*4+reg
#pragma unroll
  for (int mi = 0; mi < 2; mi++)
#pragma unroll
    for (int ni = 0; ni < 2; ni++)
#pragma unroll
      for (int r = 0; r < 4; r++) {
        int gm = m0 + wm + mi * 16 + lq * 4 + r;
        if (gm < M)
          C[(size_t)gm * N + n0 + wn + ni * 16 + lr] = f2bf(acc[mi][ni][r]);
      }

  // alpha: 64 rows x 4 parts; part&1 = column half, part&2 = src/dst
  {
    int row = tid >> 2, part = tid & 3;
    int gn = m0 + row;
    const float* av = ((part & 2) ? a_dst : a_src) + n0 + (part & 1) * 32;
    float dot = 0.f;
#pragma unroll
    for (int c = 0; c < 32; c++) dot += sm.epi.ct[row][(part & 1) * 32 + c] * av[c];
    if constexpr (HPT == 2) {
      if (gn < M) {
        float* tgt = (part & 2) ? ad : as;
        tgt[(size_t)gn * HTOT + (n0 >> 5) + (part & 1)] = dot;
      }
    } else {
      sm.epi.pr[row][part] = dot;
      __syncthreads();
      if (part == 0 && gn < M) {
        as[gn] = sm.epi.pr[row][0] + sm.epi.pr[row][1];
        ad[gn] = sm.epi.pr[row][2] + sm.epi.pr[row][3];
      }
    }
  }
}

// ---------------------------------------------------------------------------
// CSR build: histogram -> partial sums -> block_scan (re-scans the partial
// sums in LDS; no serial kernel) -> reverse bucket fill.
// ---------------------------------------------------------------------------
__global__ void deg_count(const int* __restrict__ dst, int* __restrict__ cnt) {
  int e = blockIdx.x * blockDim.x + threadIdx.x;
  if (e < N_EDGES) atomicAdd(&cnt[dst[e]], 1);
}

__global__ void partial_sum(const int* __restrict__ cnt, int* __restrict__ bsum) {
  __shared__ int s[256];
  int i = blockIdx.x * 256 + threadIdx.x;
  s[threadIdx.x] = (i < N_NODES) ? cnt[i] : 0;
  __syncthreads();
  for (int off = 128; off > 0; off >>= 1) {
    if (threadIdx.x < off) s[threadIdx.x] += s[threadIdx.x + off];
    __syncthreads();
  }
  if (threadIdx.x == 0) bsum[blockIdx.x] = s[0];
}

__global__ void block_scan(const int* __restrict__ cnt, const int* __restrict__ bsum,
                           int* __restrict__ rs, int nb) {
  __shared__ int s[256], sb[256];
  int t = threadIdx.x;
  // inclusive scan of the block partial sums (<=256 of them)
  sb[t] = (t < nb) ? bsum[t] : 0;
  __syncthreads();
  for (int off = 1; off < 256; off <<= 1) {
    int v = (t >= off) ? sb[t - off] : 0;
    __syncthreads();
    sb[t] += v;
    __syncthreads();
  }
  int base = (blockIdx.x > 0) ? sb[blockIdx.x - 1] : 0;
  // scan this block's counts
  int i = blockIdx.x * 256 + t;
  int v = (i < N_NODES) ? cnt[i] : 0;
  s[t] = v;
  __syncthreads();
  for (int off = 1; off < 256; off <<= 1) {
    int u = (t >= off) ? s[t - off] : 0;
    __syncthreads();
    s[t] += u;
    __syncthreads();
  }
  if (i < N_NODES) rs[i] = base + s[t] - v;  // exclusive
}

__global__ void fill_csr(const int* __restrict__ src, const int* __restrict__ dst,
                         const int* __restrict__ rs, int* __restrict__ cnt,
                         int* __restrict__ csr_src) {
  int e = blockIdx.x * blockDim.x + threadIdx.x;
  if (e >= N_EDGES) return;
  int d = dst[e];
  int pos = atomicSub(&cnt[d], 1) - 1;
  csr_src[rs[d] + pos] = src[e];
}

// ---------------------------------------------------------------------------
// Fused score+aggregate, layer 1. One wave per dst node, lane owns 4 feats
// (uint2 gather). Per 8-edge chunk: broadcast all 8 src indices, issue all 8
// gathers back-to-back (MLP), then w-broadcasts + FMAs.
// ---------------------------------------------------------------------------
__global__ __launch_bounds__(256) void gat_aggr1(
    const int* __restrict__ rs, const int* __restrict__ csr_src,
    const float* __restrict__ as, const float* __restrict__ ad,
    const bf16_t* __restrict__ hb, const float* __restrict__ bias,
    bf16_t* __restrict__ outp) {
  int d = blockIdx.x * 4 + (threadIdx.x >> 6);
  int lane = threadIdx.x & 63;
  if (d >= N_NODES) return;
  int beg = rs[d];
  int end = (d == N_NODES - 1) ? N_EDGES : rs[d + 1];
  const int sh = lane & 7;   // scorer head (lane scores edge lane>>3, head sh)
  const int ah = lane >> 3;  // aggregation head for feats 4*lane..4*lane+3
  float ad_h = ad[(size_t)d * 8 + sh];
  float a0 = 0.f, a1 = 0.f, a2 = 0.f, a3 = 0.f, z = 0.f;

  for (int cb = beg; cb < end; cb += 8) {
    int ei = cb + (lane >> 3);
    int s_reg = csr_src[(ei < end) ? ei : (end - 1)];
    float w_reg = (ei < end) ? lrexp(as[(size_t)s_reg * 8 + sh] + ad_h) : 0.f;
    int cnt = end - cb;
    if (cnt >= 8) {
      int sv[8];
#pragma unroll
      for (int e = 0; e < 8; e++) sv[e] = __shfl(s_reg, e << 3);
      uint2 g[8];
#pragma unroll
      for (int e = 0; e < 8; e++)
        g[e] = *reinterpret_cast<const uint2*>(&hb[(size_t)sv[e] * F1 + 4 * lane]);
#pragma unroll
      for (int e = 0; e < 8; e++) {
        float wv = __shfl(w_reg, (e << 3) | ah);
        union { uint2 u; bf16_t h[4]; } ld;
        ld.u = g[e];
        a0 += bf2f(ld.h[0]) * wv;
        a1 += bf2f(ld.h[1]) * wv;
        a2 += bf2f(ld.h[2]) * wv;
        a3 += bf2f(ld.h[3]) * wv;
        z += wv;
      }
    } else {
      for (int e = 0; e < cnt; e++) {
        float wv = __shfl(w_reg, (e << 3) | ah);
        int sv1 = __shfl(s_reg, e << 3);
        union { uint2 u; bf16_t h[4]; } ld;
        ld.u = *reinterpret_cast<const uint2*>(&hb[(size_t)sv1 * F1 + 4 * lane]);
        a0 += bf2f(ld.h[0]) * wv;
        a1 += bf2f(ld.h[1]) * wv;
        a2 += bf2f(ld.h[2]) * wv;
        a3 += bf2f(ld.h[3]) * wv;
        z += wv;
      }
    }
  }

  float inv = (end > beg) ? (1.f / z) : 0.f;
  float v0 = a0 * inv + bias[4 * lane + 0];
  float v1 = a1 * inv + bias[4 * lane + 1];
  float v2 = a2 * inv + bias[4 * lane + 2];
  float v3 = a3 * inv + bias[4 * lane + 3];
  v0 = (v0 > 0.f) ? v0 : expm1f(v0);
  v1 = (v1 > 0.f) ? v1 : expm1f(v1);
  v2 = (v2 > 0.f) ? v2 : expm1f(v2);
  v3 = (v3 > 0.f) ? v3 : expm1f(v3);
  union { bf16_t h[4]; uint2 u; } pk;
  pk.h[0] = f2bf(v0); pk.h[1] = f2bf(v1); pk.h[2] = f2bf(v2); pk.h[3] = f2bf(v3);
  *reinterpret_cast<uint2*>(&outp[(size_t)d * F1 + 4 * lane]) = pk.u;
}

// ---------------------------------------------------------------------------
// Fused score+aggregate, layer 2 (H=1, C=64). HALF-wave per dst node: lane
// owns 2 feats (uint gather; 32 lanes cover the 128 B row), 2 nodes/wave.
// Same 8-edge MLP prefetch, shuffles at width 32.
// ---------------------------------------------------------------------------
__global__ __launch_bounds__(256) void gat_aggr2(
    const int* __restrict__ rs, const int* __restrict__ csr_src,
    const float* __restrict__ as, const float* __restrict__ ad,
    const bf16_t* __restrict__ hb, const float* __restrict__ bias,
    float* __restrict__ outp) {
  int d = blockIdx.x * 8 + (threadIdx.x >> 5);
  int sub = threadIdx.x & 31;
  if (d >= N_NODES) return;
  int beg = rs[d];
  int end = (d == N_NODES - 1) ? N_EDGES : rs[d + 1];
  float ad_d = ad[d];
  float acc0 = 0.f, acc1 = 0.f, z = 0.f;

  for (int cb = beg; cb < end; cb += 32) {
    int ei = cb + sub;
    int s_reg = csr_src[(ei < end) ? ei : (end - 1)];
    float w_reg = (ei < end) ? lrexp(as[s_reg] + ad_d) : 0.f;
    int cnt = end - cb;
    if (cnt > 32) cnt = 32;
    int e0 = 0;
    for (; e0 + 8 <= cnt; e0 += 8) {
      int sv[8];
#pragma unroll
      for (int e = 0; e < 8; e++) sv[e] = __shfl(s_reg, e0 + e, 32);
      unsigned int g[8];
#pragma unroll
      for (int e = 0; e < 8; e++)
        g[e] = *reinterpret_cast<const unsigned int*>(&hb[(size_t)sv[e] * OUTC + 2 * sub]);
#pragma unroll
      for (int e = 0; e < 8; e++) {
        float wv = __shfl(w_reg, e0 + e, 32);
        union { unsigned int u; bf16_t h[2]; } ld;
        ld.u = g[e];
        acc0 += bf2f(ld.h[0]) * wv;
        acc1 += bf2f(ld.h[1]) * wv;
        z += wv;
      }
    }
    for (; e0 < cnt; e0++) {
      float wv = __shfl(w_reg, e0, 32);
      int sv1 = __shfl(s_reg, e0, 32);
      union { unsigned int u; bf16_t h[2]; } ld;
      ld.u = *reinterpret_cast<const unsigned int*>(&hb[(size_t)sv1 * OUTC + 2 * sub]);
      acc0 += bf2f(ld.h[0]) * wv;
      acc1 += bf2f(ld.h[1]) * wv;
      z += wv;
    }
  }

  float inv = (end > beg) ? (1.f / z) : 0.f;
  float2 o;
  o.x = acc0 * inv + bias[2 * sub + 0];
  o.y = acc1 * inv + bias[2 * sub + 1];
  *reinterpret_cast<float2*>(&outp[(size_t)d * OUTC + 2 * sub]) = o;
}

extern "C" void kernel_launch(void* const* d_in, const int* in_sizes, int n_in,
                              void* d_out, int out_size, void* d_ws, size_t ws_size,
                              hipStream_t stream) {
  const float* x      = (const float*)d_in[0];
  const int*   ei     = (const int*)d_in[1];
  const float* W1     = (const float*)d_in[2];
  const float* a1_src = (const float*)d_in[3];
  const float* a1_dst = (const float*)d_in[4];
  const float* b1     = (const float*)d_in[5];
  const float* W2     = (const float*)d_in[6];
  const float* a2_src = (const float*)d_in[7];
  const float* a2_dst = (const float*)d_in[8];
  const float* b2     = (const float*)d_in[9];

  const int* src = ei;
  const int* dst = ei + N_EDGES;
  float* out = (float*)d_out;

  char* base = (char*)d_ws;
  size_t off = 0;
  auto carve = [&](size_t bytes) {
    void* q = base + off;
    off += (bytes + 255) & ~size_t(255);
    return q;
  };
  bf16_t* h1b  = (bf16_t*)carve((size_t)N_NODES * F1 * 2);     // 25.6 MB
  bf16_t* o1b  = (bf16_t*)carve((size_t)N_NODES * F1 * 2);     // 25.6 MB
  bf16_t* h2b  = (bf16_t*)carve((size_t)N_NODES * OUTC * 2);   // 6.4 MB
  bf16_t* W1t  = (bf16_t*)carve((size_t)F1 * INC * 2);
  bf16_t* W2t  = (bf16_t*)carve((size_t)OUTC * F1 * 2);
  float* as1 = (float*)carve((size_t)N_NODES * HEADS * 4);
  float* ad1 = (float*)carve((size_t)N_NODES * HEADS * 4);
  float* as2 = (float*)carve((size_t)N_NODES * 4);
  float* ad2 = (float*)carve((size_t)N_NODES * 4);
  int* cnt = (int*)carve((size_t)N_NODES * 4);
  int* rs = (int*)carve((size_t)N_NODES * 4);
  int* bsum = (int*)carve(256 * 4);
  int* csr_src = (int*)carve((size_t)N_EDGES * 4);

  constexpr int NB_SCAN = (N_NODES + 255) / 256;  // 196

  // ---- prep (W transposes + cnt=0) ----
  prep_w<<<(N_NODES + 255) / 256, 256, 0, stream>>>(W1, W2, W1t, W2t, cnt);

  // ---- CSR build ----
  deg_count<<<(N_EDGES + 255) / 256, 256, 0, stream>>>(dst, cnt);
  partial_sum<<<NB_SCAN, 256, 0, stream>>>(cnt, bsum);
  block_scan<<<NB_SCAN, 256, 0, stream>>>(cnt, bsum, rs, NB_SCAN);
  fill_csr<<<(N_EDGES + 255) / 256, 256, 0, stream>>>(src, dst, rs, cnt, csr_src);

  // ---------------- layer 1 ----------------
  mfma_gemm_fused<true, 2, HEADS><<<dim3(F1 / 64, (N_NODES + 63) / 64), 256, 0, stream>>>(
      x, W1t, h1b, a1_src, a1_dst, as1, ad1, N_NODES, F1, INC);
  gat_aggr1<<<(N_NODES + 3) / 4, 256, 0, stream>>>(rs, csr_src, as1, ad1, h1b, b1, o1b);

  // ---------------- layer 2 ----------------
  mfma_gemm_fused<false, 1, 1><<<dim3(OUTC / 64, (N_NODES + 63) / 64), 256, 0, stream>>>(
      o1b, W2t, h2b, a2_src, a2_dst, as2, ad2, N_NODES, OUTC, F1);
  gat_aggr2<<<(N_NODES + 7) / 8, 256, 0, stream>>>(rs, csr_src, as2, ad2, h2b, b2, out);
}